// Round 8
// baseline (392.644 us; speedup 1.0000x reference)
//
#include <hip/hip_runtime.h>
#include <hip/hip_bf16.h>

#define H   128
#define RR  8
#define NN  8192
#define BB  64
#define LL  48
#define EE  65536
#define NPG 128          // nodes per graph (N/B)
#define VA  64
#define GPB 16           // graphs per block in gru part
#define CAP 256          // per-rgcn-block edge bucket capacity (mean 128, ~11 sigma)

typedef unsigned short u16;
typedef unsigned int   u32;

__device__ __forceinline__ float b2f(u16 u) {
    union { u32 i; float f; } v; v.i = ((u32)u) << 16; return v.f;
}
__device__ __forceinline__ u16 f2b(float f) {
    union { float f; u32 i; } v; v.f = f;
    u32 x = v.i;
    return (u16)((x + 0x7fffu + ((x >> 16) & 1u)) >> 16);
}
__device__ __forceinline__ float2 up2(u32 p) {
    union { u32 i; float f; } a, b;
    a.i = p << 16; b.i = p & 0xffff0000u;
    return make_float2(a.f, b.f);
}
__device__ __forceinline__ u32 pk2(float a, float b) {
    return ((u32)f2b(b) << 16) | (u32)f2b(a);
}
__device__ __forceinline__ float rcpf(float x) { return __builtin_amdgcn_rcpf(x); }
__device__ __forceinline__ u32 cvtpk(float lo, float hi) {   // dst={hi16:cvt(hi), lo16:cvt(lo)}
    u32 r;
    asm("v_cvt_pk_bf16_f32 %0, %1, %2" : "=v"(r) : "v"(lo), "v"(hi));
    return r;
}

#define K_LOG2E  1.4426950408889634f
#define K_2LOG2E 2.8853900817779268f

typedef __attribute__((ext_vector_type(8))) short bf16x8;
typedef __attribute__((ext_vector_type(4))) float f32x4;
typedef __attribute__((ext_vector_type(4))) unsigned short u16x4;

// ---------------- fused prep: zero bucket cursors + embed nodes + weight tiling ----------------
__global__ __launch_bounds__(256) void k_prep(const int* __restrict__ nodeTypes,
                                              const float* __restrict__ emb_nodes,
                                              const float* __restrict__ rel,
                                              const float* __restrict__ root,
                                              const float* __restrict__ w_ih,
                                              float* __restrict__ x0,
                                              u16* __restrict__ WTt,
                                              u16* __restrict__ WTih,
                                              float* __restrict__ hGsum,
                                              int* __restrict__ bcnt) {
    int idx = blockIdx.x * 256 + threadIdx.x;
    if (idx < 512) bcnt[idx] = 0;
    if (idx < 384 * H) WTih[idx] = f2b(w_ih[idx]);
    if (idx < BB * H) hGsum[idx] = 0.f;
    if (idx < NN * H) {
        int n = idx >> 7, h = idx & (H - 1);
        x0[idx] = emb_nodes[(size_t)nodeTypes[n] * H + h];
    }
    int j = idx - NN * H;
    if (j < 0 || j >= 3 * 147456) return;
    int li  = j / 147456;
    int rem = j - li * 147456;
    int tile = rem / 36864;
    int r2   = rem - tile * 36864;
    int ks   = r2 / 1024;
    int r3   = r2 - ks * 1024;
    int sub  = r3 >> 9;
    int r4   = r3 & 511;
    int lane = r4 >> 3, jj = r4 & 7;
    int col = tile * 32 + sub * 16 + (lane & 15);
    int k   = ks * 32 + (lane >> 4) * 8 + jj;
    float v;
    if (k < 1024) v = rel[(((size_t)li * RR + (k >> 7)) * H + (k & 127)) * H + col];
    else          v = root[((size_t)li * H + (k - 1024)) * H + col];
    WTt[j] = f2b(v);
}

// ---------------- scatter edges into per-rgcn-block buckets (replaces 5-kernel CSR) ----------------
// entry = src | segLocal<<16, segLocal = (dst&15)*8 + rel  [round-6 verified]
__global__ __launch_bounds__(256) void k_bucket(const int* __restrict__ edge_index,
                                                const int* __restrict__ edge_attr,
                                                int* __restrict__ bcnt,
                                                u32* __restrict__ bucket) {
    int e = blockIdx.x * 256 + threadIdx.x;
    if (e < EE) {
        int dst = edge_index[EE + e];
        int blk = dst >> 4;
        int pos = atomicAdd(&bcnt[blk], 1);
        if (pos < CAP) {
            u32 sl = (u32)(((dst & 15) << 3) | edge_attr[e]);
            bucket[(size_t)blk * CAP + pos] = (u32)edge_index[e] | (sl << 16);
        }
    }
}

// ---------------- one RGCN layer (8 waves; bucket + in-LDS segment ordering) ----------------
// Phase A serial-per-segment gather is the round-7 verified body; only the edge
// list construction changed: counts via 128-entry LDS int atomics + local scan
// (NOT round-6's f32 aggregation storm). All edges LDS-resident (ne <= CAP).
#define RGN 16           // nodes per block; grid = 512

__global__ __launch_bounds__(512) void k_rgcn(const float* __restrict__ xin,
                                              float* __restrict__ xout,
                                              const u16* __restrict__ WTt,    // fragment-tiled
                                              const float* __restrict__ bias, // [H]
                                              const int* __restrict__ bcnt,
                                              const u32* __restrict__ bucket,
                                              float* __restrict__ hGsum) {   // null except L3
    __shared__ u32 ab[RGN * 580];          // 37.1 KB bf16-packed A (row stride 580)
    __shared__ u32 ebuf[CAP];
    __shared__ u16 srcl[CAP];              // segment-ordered src list
    __shared__ int cnt[RGN * RR], incl[RGN * RR], cur[RGN * RR];
    int tid = threadIdx.x, wv = tid >> 6, lane = tid & 63;   // wv 0..7
    int blk = blockIdx.x, n0 = blk * RGN;
    int ne = min(bcnt[blk], CAP);

    for (int i = tid; i < ne; i += 512) ebuf[i] = bucket[(size_t)blk * CAP + i];
    if (tid < RGN * RR) { cnt[tid] = 0; cur[tid] = 0; }
    __syncthreads();
    for (int i = tid; i < ne; i += 512) atomicAdd(&cnt[ebuf[i] >> 16], 1);
    __syncthreads();
    if (tid < RGN * RR) incl[tid] = cnt[tid];
    __syncthreads();
    for (int off = 1; off < RGN * RR; off <<= 1) {   // inclusive scan, 7 rounds
        int v = 0;
        if (tid < RGN * RR && tid >= off) v = incl[tid - off];
        __syncthreads();
        if (tid < RGN * RR) incl[tid] += v;
        __syncthreads();
    }
    for (int i = tid; i < ne; i += 512) {
        int sl = ebuf[i] >> 16;
        int pos = (incl[sl] - cnt[sl]) + atomicAdd(&cur[sl], 1);
        srcl[pos] = (u16)(ebuf[i] & 0xffffu);
    }
    __syncthreads();

    // phase A: wave per segment (16 per wave); lanes cover H via float2
    for (int s = wv; s < RGN * RR; s += 8) {
        int end = incl[s], beg = end - cnt[s];
        float a0 = 0.f, a1 = 0.f;
        for (int e = beg; e < end; ++e) {
            int src = srcl[e];
            float2 v = ((const float2*)(xin + (size_t)src * H))[lane];
            a0 += v.x; a1 += v.y;
        }
        float inv = 1.f / fmaxf((float)(end - beg), 1.f);
        ab[(s >> 3) * 580 + ((s & 7) << 6) + lane] = pk2(a0 * inv, a1 * inv);
    }
    // root block: k-pair slots 512..575
    for (int i = wv; i < RGN; i += 8) {
        const float* xr = xin + (size_t)(n0 + i) * H + 2 * lane;
        ab[i * 580 + 512 + lane] = pk2(xr[0], xr[1]);
    }
    __syncthreads();

    // MFMA GEMM: wave = 16-col tile (tile=wv>>1, sub=wv&1); 36 ksteps 16x16x32
    int m = lane & 15, quad = lane >> 4;
    const u32* aP = ab + m * 580 + quad * 4;
    const u32* bT = (const u32*)WTt + (size_t)(wv >> 1) * 36 * 512 + (wv & 1) * 256 + lane * 4;
    f32x4 acc0 = {0.f, 0.f, 0.f, 0.f};
    bf16x8 b0c = *(const bf16x8*)bT;
    for (int ks = 0; ks < 36; ++ks) {
        bf16x8 b0n;
        if (ks < 35) b0n = *(const bf16x8*)(bT + (ks + 1) * 512);
        bf16x8 a = *(const bf16x8*)(aP + ks * 16);
        acc0 = __builtin_amdgcn_mfma_f32_16x16x32_bf16(a, b0c, acc0, 0, 0, 0);
        b0c = b0n;
    }
    int c0 = wv * 16 + m;
    float bv0 = bias[c0];
    float so0 = 0.f;
#pragma unroll
    for (int rg = 0; rg < 4; ++rg) {
        int n = n0 + quad * 4 + rg;
        float o0 = fmaxf(acc0[rg] + bv0, 0.f);
        xout[(size_t)n * H + c0] = o0;
        so0 += o0;
    }
    if (hGsum) {      // fused mean-pool partial sums (layer 3 only)
        so0 += __shfl_xor(so0, 16, 64);
        so0 += __shfl_xor(so0, 32, 64);
        if (quad == 0) {
            int g = n0 >> 7;
            atomicAdd(&hGsum[g * H + c0], so0);
        }
    }
}

// ---------------- fused action head + sequence pooling (heterogeneous grid) ----------------
__global__ __launch_bounds__(256) void k_pool_seq(const float* __restrict__ hGsum,
                                                  const int* __restrict__ nodes_bs,
                                                  const float* __restrict__ linA_w,
                                                  const float* __restrict__ linA_b,
                                                  const float* __restrict__ linAf_w,
                                                  const float* __restrict__ linAf_b,
                                                  float* __restrict__ hG,
                                                  float* __restrict__ out,
                                                  const float* __restrict__ xf,
                                                  const float* __restrict__ seq,
                                                  const float* __restrict__ emb_actions,
                                                  const int* __restrict__ action_input,
                                                  float* __restrict__ igG) {
    __shared__ float xg[64][H];        // 32 KB (pool part reuses rows 0,1)
    __shared__ u16 lists[LL][64];      // 6 KB
    __shared__ int cnts[LL];
    int tid = threadIdx.x;

    if (blockIdx.x < BB) {
        // ---------------- action head ----------------
        float* hgs = &xg[0][0];
        float* t1  = &xg[1][0];
        int b = blockIdx.x, h = tid;
        if (h < H) {
            float hg = hGsum[(size_t)b * H + h] / (float)nodes_bs[b];
            hG[(size_t)b * H + h] = hg;
            hgs[h] = hg;
        }
        __syncthreads();
        if (h < H) {
            float acc = linA_b[h];
            const float* wr = linA_w + (size_t)h * H;
            for (int k = 0; k < H; ++k) acc += wr[k] * hgs[k];
            t1[h] = fmaxf(acc, 0.f);
        }
        __syncthreads();
        if (h < VA) {
            float a = linAf_b[h];
            const float* w2 = linAf_w + (size_t)h * H;
            for (int k = 0; k < H; ++k) a += w2[k] * t1[k];
            out[(size_t)b * VA + h] = a;
        }
        return;
    }

    // ---------------- sequence pooling -> SHIFTED GRU input igG ----------------
    int b = blockIdx.x - BB;
    int col = tid & 127, tg = tid >> 7;
    float acc[24];
#pragma unroll
    for (int m = 0; m < 24; ++m) acc[m] = 0.f;

    for (int chunk = 0; chunk < 2; ++chunk) {
        int i0 = b * NPG + chunk * 64;
        __syncthreads();
        if (tid < LL) cnts[tid] = 0;
        __syncthreads();
        for (int idx = tid; idx < 64 * H / 4; idx += 256)
            ((float4*)&xg[0][0])[idx] = ((const float4*)(xf + (size_t)i0 * H))[idx];
        for (int idx = tid; idx < 64 * LL; idx += 256) {
            int i = idx / LL, t = idx - i * LL;
            if (seq[(size_t)(i0 + i) * LL + t] != 0.f) {
                int p = atomicAdd(&cnts[t], 1);
                lists[t][p] = (u16)i;
            }
        }
        __syncthreads();
        for (int m = 0; m < 24; ++m) {
            int t = tg + 2 * m;
            int c = cnts[t];
            float a = acc[m];
            for (int p = 0; p < c; ++p) a += xg[lists[t][p]][col];
            acc[m] = a;
        }
    }
    if (tid < H)
        igG[((size_t)b * LL) * H + tid] = emb_actions[(size_t)action_input[b] * H + tid];
#pragma unroll
    for (int m = 0; m < 24; ++m) {
        int t = tg + 2 * m;
        if (t < LL - 1)
            igG[((size_t)b * LL + t + 1) * H + col] = acc[m];
    }
}

// ---------------- xw GEMM -> COALESCED gru layout ----------------
// xw3[gblk][t][wv(8)][gate(3)][quad(4)][mi(16)][4] bf16, pre-scaled for exp2:
//   r,z gates (incl folded b_hh): * log2e;  n gate (b_ih only): * 2*log2e.
__global__ __launch_bounds__(256) void k_xw(const float* __restrict__ igG,
                                            const u16* __restrict__ WTih,
                                            const float* __restrict__ b_ih,
                                            const float* __restrict__ b_hh,
                                            u16* __restrict__ xwG) {
    __shared__ u32 ab[16 * 68];        // 4.35 KB, stride 68
    int tid = threadIdx.x, wv = tid >> 6, lane = tid & 63;
    int n0 = blockIdx.x * 16;
    for (int s = tid; s < 16 * 64; s += 256) {
        int row = s >> 6, kp = s & 63;
        float2 v = *(const float2*)(igG + (size_t)(n0 + row) * H + 2 * kp);
        ab[row * 68 + kp] = pk2(v.x, v.y);
    }
    __syncthreads();
    int m = lane & 15, quad = lane >> 4;
    const u32* aP = ab + m * 68 + quad * 4;
    f32x4 acc[6];
#pragma unroll
    for (int i = 0; i < 6; ++i) acc[i] = (f32x4){0.f, 0.f, 0.f, 0.f};
#pragma unroll
    for (int ks = 0; ks < 4; ++ks) {
        bf16x8 a = *(const bf16x8*)(aP + ks * 16);
#pragma unroll
        for (int tc = 0; tc < 6; ++tc) {
            int colr = wv * 96 + tc * 16 + m;
            bf16x8 bfr = *(const bf16x8*)((const u32*)WTih + (size_t)colr * 64 + quad * 4 + ks * 16);
            acc[tc] = __builtin_amdgcn_mfma_f32_16x16x32_bf16(a, bfr, acc[tc], 0, 0, 0);
        }
    }
#pragma unroll
    for (int tc = 0; tc < 6; ++tc) {
        int c = wv * 96 + tc * 16 + m;
        // fold b_hh for r,z gates; n-gate's b_hh seeds the acc in the gru.
        float bv = b_ih[c] + ((c < 256) ? b_hh[c] : 0.f);
        float sc = (c < 256) ? K_LOG2E : K_2LOG2E;   // exp2 pre-scale
        int R = c & 127, gate = c >> 7;
#pragma unroll
        for (int rg = 0; rg < 4; ++rg) {
            int r = n0 + quad * 4 + rg;
            int bb = r / 48, tt = r - bb * 48;
            size_t o = (((((size_t)(bb >> 4) * LL + tt) * 8 + (R >> 4)) * 3 + gate) * 256)
                     + (((R >> 2) & 3) << 6) + ((bb & 15) << 2) + (R & 3);
            xwG[o] = f2b((acc[tc][rg] + bv) * sc);
        }
    }
}

// ---------------- fused GRU + Bx (heterogeneous grid) ----------------
// Blocks 0..3: batched MFMA GRU (harness-verified body). Blocks 4..259:
// Bx[n,:] = W1b @ x[n] + linN_b (bf16), 32 nodes/block, hidden under GRU.
#define GRU_BLKS 4
#define BX_BLKS  (NN / 32)     // 256
#define SMEM_BYTES 33024       // max(gru 16384, bx 16384+16640)

__global__ __launch_bounds__(512) void k_gru_bx(const u16* __restrict__ xw2,
                                                const float* __restrict__ hG,
                                                const float* __restrict__ w_hh,
                                                const float* __restrict__ b_hh,
                                                const int* __restrict__ len_seq,
                                                float* __restrict__ soutG,
                                                const float* __restrict__ xf,
                                                const float* __restrict__ linN_w,
                                                const float* __restrict__ linN_b,
                                                u16* __restrict__ BxU) {
    __shared__ __align__(16) char smem[SMEM_BYTES];
    int tid = threadIdx.x;

    if (blockIdx.x >= GRU_BLKS) {
        // ---------------- Bx part: 32 nodes, 512 threads ----------------
        float* xl = (float*)smem;                    // [32][128], 16 KB
        float* wb = (float*)(smem + 16384);          // [32][130], 16.6 KB
        int bid = blockIdx.x - GRU_BLKS;
        int n0 = bid * 32;
        for (int idx = tid; idx < 32 * H; idx += 512)
            xl[idx] = xf[(size_t)n0 * H + idx];
        int col = tid & 127, g = tid >> 7;           // g 0..3, 8 nodes each
        float bv = linN_b[col];
        float acc[8] = {bv, bv, bv, bv, bv, bv, bv, bv};
        for (int c = 0; c < 4; ++c) {
            int k0 = c * 32;
            __syncthreads();
            for (int idx = tid; idx < 32 * H; idx += 512) {
                int r = idx >> 5, kk = idx & 31;
                wb[kk * 130 + r] = linN_w[(size_t)r * (2 * H) + H + k0 + kk];
            }
            __syncthreads();
#pragma unroll
            for (int kk = 0; kk < 32; ++kk) {
                float w = wb[kk * 130 + col];
#pragma unroll
                for (int j = 0; j < 8; ++j) acc[j] += xl[(g * 8 + j) * H + k0 + kk] * w;
            }
        }
#pragma unroll
        for (int j = 0; j < 8; ++j)
            BxU[(size_t)(n0 + g * 8 + j) * H + col] = f2b(acc[j]);
        return;
    }

    // ---------------- GRU part ----------------
    u16* hA = (u16*)smem;    // [2][2][2048]: (buf*2+hl)*2048 + e, 16 KB
    int lane = tid & 63, wv = tid >> 6;       // wv 0..7
    int mi = lane & 15, quad = lane >> 4;     // mi = graph col
    int gblk = blockIdx.x;
    int g_abs = gblk * GPB + mi;
    int R0 = 16 * wv + 4 * quad;              // this lane's 4 h-rows [R0, R0+4)

    // fragment-order write slot for rows R0..R0+3 of graph mi:
    //   row R -> (ks=R>>5, lane'=mi+16*((R>>3)&3), j=R&7); reg r=0..3 -> j0+r.
    int eW = (((wv >> 1) * 64) + (mi + 16 * ((2 * wv + (quad >> 1)) & 3))) * 8
             + 4 * (quad & 1);

    // W_hh A-fragments, register-resident: 3 tiles (r,z,n), 4 ks each = 48 VGPR.
    // Pre-scaled: r,z by log2e; n by 2*log2e (exact, folded into bf16 quantize).
    bf16x8 wfr[3][4];
#pragma unroll
    for (int gate = 0; gate < 3; ++gate) {
        int T = wv + 8 * gate;
        float sc = (gate == 2) ? K_2LOG2E : K_LOG2E;
#pragma unroll
        for (int ks = 0; ks < 4; ++ks) {
            const float* wp = w_hh + (size_t)(16 * T + mi) * H + quad * 8 + ks * 32;
            float4 f0 = *(const float4*)wp;
            float4 f1 = *(const float4*)(wp + 4);
            bf16x8 v;
            v[0] = (short)f2b(f0.x * sc); v[1] = (short)f2b(f0.y * sc);
            v[2] = (short)f2b(f0.z * sc); v[3] = (short)f2b(f0.w * sc);
            v[4] = (short)f2b(f1.x * sc); v[5] = (short)f2b(f1.y * sc);
            v[6] = (short)f2b(f1.z * sc); v[7] = (short)f2b(f1.w * sc);
            wfr[gate][ks] = v;
        }
    }
    float4 bn = *(const float4*)(b_hh + 256 + R0);     // n-gate bias (acc seed)
    float4 h0 = *(const float4*)(hG + (size_t)g_abs * H + R0);
    int ls = len_seq[g_abs];

    float hp[4]  = {h0.x, h0.y, h0.z, h0.w};
    float bnn[4] = {bn.x * K_2LOG2E, bn.y * K_2LOG2E, bn.z * K_2LOG2E, bn.w * K_2LOG2E};

    auto storeh = [&](int buf, const float* hv) {
        u32 w0 = cvtpk(hv[0], hv[1]);
        u32 w1 = cvtpk(hv[2], hv[3]);
        float2 e0 = up2(w0), e1 = up2(w1);
        u32 l0 = cvtpk(hv[0] - e0.x, hv[1] - e0.y);    // hi+lo: ~17-bit h mantissa
        u32 l1 = cvtpk(hv[2] - e1.x, hv[3] - e1.y);
        *(uint2*)&hA[buf * 4096 + eW]        = make_uint2(w0, w1);
        *(uint2*)&hA[buf * 4096 + 2048 + eW] = make_uint2(l0, l1);
    };
    auto loadxw = [&](int t, u16x4* d) {
        const u16* p = xw2 + ((((size_t)gblk * LL + t) * 8 + wv) * 3) * 256
                     + (quad << 6) + (mi << 2);
        d[0] = *(const u16x4*)(p);          // r   (512B coalesced per wave)
        d[1] = *(const u16x4*)(p + 256);    // z
        d[2] = *(const u16x4*)(p + 512);    // n
    };

    auto step = [&](int t, const u16x4* x, int buf) {
        f32x4 acc[3];
        acc[0] = (f32x4){0.f, 0.f, 0.f, 0.f};
        acc[1] = (f32x4){0.f, 0.f, 0.f, 0.f};
        acc[2] = (f32x4){bnn[0], bnn[1], bnn[2], bnn[3]};
#pragma unroll
        for (int ks = 0; ks < 4; ++ks) {
            const int e = (ks * 64 + lane) * 8;           // own 16B, conflict-free
            bf16x8 bh = *(const bf16x8*)&hA[buf * 4096 + e];
            bf16x8 bl = *(const bf16x8*)&hA[buf * 4096 + 2048 + e];
#pragma unroll
            for (int gate = 0; gate < 3; ++gate) {
                acc[gate] = __builtin_amdgcn_mfma_f32_16x16x32_bf16(wfr[gate][ks], bh, acc[gate], 0, 0, 0);
                acc[gate] = __builtin_amdgcn_mfma_f32_16x16x32_bf16(wfr[gate][ks], bl, acc[gate], 0, 0, 0);
            }
        }
        float hv[4];
        float4 so;
#pragma unroll
        for (int r = 0; r < 4; ++r) {
            float xr = b2f(x[0][r]);                      // pre-scaled by log2e
            float xz = b2f(x[1][r]);
            float xn = b2f(x[2][r]);                      // pre-scaled by 2log2e
            float rg = rcpf(1.f + __builtin_amdgcn_exp2f(-(xr + acc[0][r])));
            float zg = rcpf(1.f + __builtin_amdgcn_exp2f(-(xz + acc[1][r])));
            float u  = xn + rg * acc[2][r];               // = 2*log2e*(true u)
            float ng = 1.f - 2.f * rcpf(__builtin_amdgcn_exp2f(u) + 1.f);
            float hn = ng + zg * (hp[r] - ng);
            hp[r] = hn;
            hv[r] = hn;
            ((float*)&so)[r] = (t < ls) ? hn : 0.f;       // pad_packed mask
        }
        *(float4*)(soutG + ((size_t)g_abs * LL + t) * H + R0) = so;
        storeh(buf ^ 1, hv);
    };

    u16x4 xa[3], xb[3];
    loadxw(0, xa);
    loadxw(1, xb);
    storeh(0, hp);
    asm volatile("s_waitcnt lgkmcnt(0)\n\ts_barrier" ::: "memory");

    for (int t = 0; t < LL; t += 2) {
        step(t, xa, 0);
        if (t + 2 < LL) loadxw(t + 2, xa);
        // LDS-only barrier: do NOT drain vmcnt (stores/prefetch stay in flight)
        asm volatile("s_waitcnt lgkmcnt(0)\n\ts_barrier" ::: "memory");
        step(t + 1, xb, 1);
        if (t + 3 < LL) loadxw(t + 3, xb);
        asm volatile("s_waitcnt lgkmcnt(0)\n\ts_barrier" ::: "memory");
    }
}

// ---------------- fused node head: A2 + logits + softmax, one block per graph ----------------
// Phase 1 = round-7 k_a2 body (48 rows, A2 stays in LDS); phase 2 = round-7
// k_logits body (bxs padded to 65 u32/row: stride-64 would be a 32-way bank
// conflict); phase 3 = round-7 k_softmax body (8 segs x 16 nodes). Removes the
// logits global round-trip and 7/8 of the linN_w/A2 re-reads.
#define OUT_SMEM 95232

__global__ __launch_bounds__(512) void k_out(const float* __restrict__ soutG,
                                             const u16* __restrict__ BxU,
                                             const float* __restrict__ linN_w,
                                             const float* __restrict__ linNf_w,
                                             float* __restrict__ out) {
    __shared__ __align__(16) char sm[OUT_SMEM];
    float* xl  = (float*)sm;                 // [48][128]      phase 1 (24576)
    float* wb  = (float*)(sm + 24576);       // [32][130]      phase 1 (16640)
    float* a2s = (float*)(sm + 41216);       // [48][130]      (24960)
    float* w2s = (float*)(sm + 66176);       // [128]          (512)
    u32*   bxs = (u32*)sm;                   // [128][65]      phase 2, overlays xl/wb (33280)
    float* lg  = (float*)(sm + 66688);       // [128][49]      (25088)
    float* pm  = (float*)(sm + 91776);       // [8][48]
    float* ps  = (float*)(sm + 93312);       // [8][48]
    float* mv  = (float*)(sm + 94848);       // [48]
    float* inv = (float*)(sm + 95040);       // [48]
    int tid = threadIdx.x;
    int g = blockIdx.x;
    int col = tid & 127, grp = tid >> 7;     // grp 0..3 -> 12 rows each

    // ---- phase 1: a2s[t][col] = sum_k linN_w[col][k] * sout[g][t][k] ----
    for (int i = tid; i < LL * H; i += 512)
        xl[i] = soutG[(size_t)g * LL * H + i];
    if (tid < H) w2s[tid] = linNf_w[tid];
    float acc[12];
#pragma unroll
    for (int j = 0; j < 12; ++j) acc[j] = 0.f;
    for (int c = 0; c < 4; ++c) {
        int k0 = c * 32;
        __syncthreads();
        for (int i = tid; i < 32 * H; i += 512) {
            int r = i >> 5, kk = i & 31;
            wb[kk * 130 + r] = linN_w[(size_t)r * (2 * H) + k0 + kk];
        }
        __syncthreads();
#pragma unroll
        for (int kk = 0; kk < 32; ++kk) {
            float w = wb[kk * 130 + col];
#pragma unroll
            for (int j = 0; j < 12; ++j)
                acc[j] += xl[(grp * 12 + j) * H + k0 + kk] * w;
        }
    }
#pragma unroll
    for (int j = 0; j < 12; ++j) a2s[(grp * 12 + j) * 130 + col] = acc[j];

    // ---- phase 2: lg[n][t] = sum_k w2[k]*relu(a2s[t][k]+Bx[n][k]) ----
    __syncthreads();   // xl/wb reads done -> bxs may overlay
    for (int i = tid; i < 128 * 64; i += 512) {
        int n = i >> 6, cc = i & 63;
        bxs[n * 65 + cc] = ((const u32*)BxU)[((size_t)g * 128 + n) * 64 + cc];
    }
    __syncthreads();
#pragma unroll
    for (int m = 0; m < 12; ++m) {
        int t = grp * 12 + m;
        float a = 0.f;
#pragma unroll
        for (int kp = 0; kp < 64; ++kp) {
            float2 a2 = *(const float2*)&a2s[t * 130 + 2 * kp];
            float2 bx = up2(bxs[col * 65 + kp]);
            float2 w  = *(const float2*)&w2s[2 * kp];
            a += w.x * fmaxf(a2.x + bx.x, 0.f) + w.y * fmaxf(a2.y + bx.y, 0.f);
        }
        lg[col * 49 + t] = a;
    }

    // ---- phase 3: softmax over nodes per t; write output ----
    __syncthreads();
    int t3 = tid & 63, seg = tid >> 6;       // 8 segs x 16 nodes
    if (t3 < LL) {
        float mx = -1e30f;
        int nb = seg * 16;
        for (int n = nb; n < nb + 16; ++n) mx = fmaxf(mx, lg[n * 49 + t3]);
        pm[seg * 48 + t3] = mx;
    }
    __syncthreads();
    if (tid < LL) {
        float mx = pm[tid];
#pragma unroll
        for (int q = 1; q < 8; ++q) mx = fmaxf(mx, pm[q * 48 + tid]);
        mv[tid] = mx;
    }
    __syncthreads();
    if (t3 < LL) {
        float mx = mv[t3], s = 0.f;
        int nb = seg * 16;
        for (int n = nb; n < nb + 16; ++n) {
            float e = __expf(lg[n * 49 + t3] - mx);
            lg[n * 49 + t3] = e;
            s += e;
        }
        ps[seg * 48 + t3] = s;
    }
    __syncthreads();
    if (tid < LL) {
        float s = 0.f;
#pragma unroll
        for (int q = 0; q < 8; ++q) s += ps[q * 48 + tid];
        inv[tid] = 1.f / s;
    }
    __syncthreads();
    for (int i = tid; i < 128 * LL; i += 512) {
        int n = i / LL, tt = i - n * LL;
        out[(size_t)BB * VA + ((size_t)g * 128 + n) * LL + tt] = lg[n * 49 + tt] * inv[tt];
    }
}

// ---------------- launch ----------------
extern "C" void kernel_launch(void* const* d_in, const int* in_sizes, int n_in,
                              void* d_out, int out_size, void* d_ws, size_t ws_size,
                              hipStream_t stream) {
    (void)in_sizes; (void)n_in; (void)out_size; (void)ws_size;
    const int*   nodeTypes    = (const int*)d_in[0];
    const int*   edge_index   = (const int*)d_in[1];
    const int*   edge_attr    = (const int*)d_in[2];
    const int*   nodes_bs     = (const int*)d_in[4];
    const int*   len_seq      = (const int*)d_in[5];
    const float* seq_in       = (const float*)d_in[6];
    const int*   action_input = (const int*)d_in[7];
    const float* emb_nodes    = (const float*)d_in[8];
    const float* emb_actions  = (const float*)d_in[9];
    const float* rgcn_rel     = (const float*)d_in[10];
    const float* rgcn_root    = (const float*)d_in[11];
    const float* rgcn_bias    = (const float*)d_in[12];
    const float* gru_w_ih     = (const float*)d_in[13];
    const float* gru_w_hh     = (const float*)d_in[14];
    const float* gru_b_ih     = (const float*)d_in[15];
    const float* gru_b_hh     = (const float*)d_in[16];
    const float* linA_w       = (const float*)d_in[17];
    const float* linA_b       = (const float*)d_in[18];
    const float* linAf_w      = (const float*)d_in[19];
    const float* linAf_b      = (const float*)d_in[20];
    const float* linN_w       = (const float*)d_in[21];
    const float* linN_b       = (const float*)d_in[22];
    const float* linNf_w      = (const float*)d_in[23];
    // linNf_b cancels in the softmax

    char* w = (char*)d_ws;
    float* x0      = (float*)(w + 0);          // [0,4MB) emb ping; dead after rgcn L3
    u16*   xwG     = (u16*)  (w + 0);          //   overlay (after L3): [0, 2,359,296)
    float* soutG   = (float*)(w + 2359296);    //   overlay (after L3): [.., 3,932,160)
    float* x1      = (float*)(w + 4194304);    // [4MB,8MB) final x f32 (live to end)
    float* igG     = (float*)(w + 8388608);    // [8MB, 9,961,472) shifted GRU input
    u16*   BxU     = (u16*)  (w + 9961472);    // [9,961,472, 12,058,624)
    float* hGsum   = (float*)(w + 9969664);    //   overlay on BxU + 8 KB (dead by k_gru_bx)
    int*   bcnt    = (int*)  (w + 11567104);   //   overlay on BxU (dead by k_gru_bx), 2 KB
    u16*   WTih    = (u16*)  (w + 11829760);   //   overlay on BxU tail (dead after k_xw)
    float* hG      = (float*)(w + 12058624);   // 32 KB
    u32*   bucket  = (u32*)  (w + 12091904);   // 512 KB = 512 blocks x CAP x 4B; dead after L3
    u16*   WT      = (u16*)  (w + 12616192);   // rgcn weights bf16 (tiled), 884,736 B

    float* out_f = (float*)d_out;

    k_prep<<<dim3(5824), dim3(256), 0, stream>>>(nodeTypes, emb_nodes, rgcn_rel,
        rgcn_root, gru_w_ih, x0, WT, WTih, hGsum, bcnt);
    k_bucket<<<dim3(256), dim3(256), 0, stream>>>(edge_index, edge_attr, bcnt, bucket);

    const int rg_grid = NN / RGN;   // 512
    k_rgcn<<<dim3(rg_grid), dim3(512), 0, stream>>>(x0, x1,
        WT + 0 * 147456, rgcn_bias + 0 * H, bcnt, bucket, nullptr);
    k_rgcn<<<dim3(rg_grid), dim3(512), 0, stream>>>(x1, x0,
        WT + 1 * 147456, rgcn_bias + 1 * H, bcnt, bucket, nullptr);
    k_rgcn<<<dim3(rg_grid), dim3(512), 0, stream>>>(x0, x1,
        WT + 2 * 147456, rgcn_bias + 2 * H, bcnt, bucket, hGsum);
    // x_final = x1 (x0 region free from here)

    k_pool_seq<<<dim3(2 * BB), dim3(256), 0, stream>>>(hGsum, nodes_bs, linA_w, linA_b,
        linAf_w, linAf_b, hG, out_f, x1, seq_in, emb_actions, action_input, igG);
    k_xw<<<dim3(BB * LL / 16), dim3(256), 0, stream>>>(igG, WTih, gru_b_ih, gru_b_hh, xwG);
    k_gru_bx<<<dim3(GRU_BLKS + BX_BLKS), dim3(512), 0, stream>>>(xwG, hG, gru_w_hh,
        gru_b_hh, len_seq, soutG, x1, linN_w, linN_b, BxU);
    k_out<<<dim3(BB), dim3(512), 0, stream>>>(soutG, BxU, linN_w, linNf_w, out_f);
}

// Round 9
// 321.073 us; speedup vs baseline: 1.2229x; 1.2229x over previous
//
#include <hip/hip_runtime.h>
#include <hip/hip_bf16.h>

#define H   128
#define RR  8
#define NN  8192
#define BB  64
#define LL  48
#define EE  65536
#define NPG 128          // nodes per graph (N/B)
#define VA  64
#define GPB 16           // graphs per block in gru part
#define CAP 256          // per-rgcn-block edge bucket capacity (mean 128, ~11 sigma)

typedef unsigned short u16;
typedef unsigned int   u32;

__device__ __forceinline__ float b2f(u16 u) {
    union { u32 i; float f; } v; v.i = ((u32)u) << 16; return v.f;
}
__device__ __forceinline__ u16 f2b(float f) {
    union { float f; u32 i; } v; v.f = f;
    u32 x = v.i;
    return (u16)((x + 0x7fffu + ((x >> 16) & 1u)) >> 16);
}
__device__ __forceinline__ float2 up2(u32 p) {
    union { u32 i; float f; } a, b;
    a.i = p << 16; b.i = p & 0xffff0000u;
    return make_float2(a.f, b.f);
}
__device__ __forceinline__ u32 pk2(float a, float b) {
    return ((u32)f2b(b) << 16) | (u32)f2b(a);
}
__device__ __forceinline__ float rcpf(float x) { return __builtin_amdgcn_rcpf(x); }
__device__ __forceinline__ u32 cvtpk(float lo, float hi) {   // dst={hi16:cvt(hi), lo16:cvt(lo)}
    u32 r;
    asm("v_cvt_pk_bf16_f32 %0, %1, %2" : "=v"(r) : "v"(lo), "v"(hi));
    return r;
}

#define K_LOG2E  1.4426950408889634f
#define K_2LOG2E 2.8853900817779268f

typedef __attribute__((ext_vector_type(8))) short bf16x8;
typedef __attribute__((ext_vector_type(4))) float f32x4;
typedef __attribute__((ext_vector_type(4))) unsigned short u16x4;

// ---------------- fused prep: zero bucket cursors + embed nodes + weight tiling ----------------
__global__ __launch_bounds__(256) void k_prep(const int* __restrict__ nodeTypes,
                                              const float* __restrict__ emb_nodes,
                                              const float* __restrict__ rel,
                                              const float* __restrict__ root,
                                              const float* __restrict__ w_ih,
                                              float* __restrict__ x0,
                                              u16* __restrict__ WTt,
                                              u16* __restrict__ WTih,
                                              float* __restrict__ hGsum,
                                              int* __restrict__ bcnt) {
    int idx = blockIdx.x * 256 + threadIdx.x;
    if (idx < 512) bcnt[idx] = 0;
    if (idx < 384 * H) WTih[idx] = f2b(w_ih[idx]);
    if (idx < BB * H) hGsum[idx] = 0.f;
    if (idx < NN * H) {
        int n = idx >> 7, h = idx & (H - 1);
        x0[idx] = emb_nodes[(size_t)nodeTypes[n] * H + h];
    }
    int j = idx - NN * H;
    if (j < 0 || j >= 3 * 147456) return;
    int li  = j / 147456;
    int rem = j - li * 147456;
    int tile = rem / 36864;
    int r2   = rem - tile * 36864;
    int ks   = r2 / 1024;
    int r3   = r2 - ks * 1024;
    int sub  = r3 >> 9;
    int r4   = r3 & 511;
    int lane = r4 >> 3, jj = r4 & 7;
    int col = tile * 32 + sub * 16 + (lane & 15);
    int k   = ks * 32 + (lane >> 4) * 8 + jj;
    float v;
    if (k < 1024) v = rel[(((size_t)li * RR + (k >> 7)) * H + (k & 127)) * H + col];
    else          v = root[((size_t)li * H + (k - 1024)) * H + col];
    WTt[j] = f2b(v);
}

// ---------------- scatter edges into per-rgcn-block buckets (replaces 5-kernel CSR) ----------------
// entry = src | segLocal<<16, segLocal = (dst&15)*8 + rel  [round-6/8 verified]
__global__ __launch_bounds__(256) void k_bucket(const int* __restrict__ edge_index,
                                                const int* __restrict__ edge_attr,
                                                int* __restrict__ bcnt,
                                                u32* __restrict__ bucket) {
    int e = blockIdx.x * 256 + threadIdx.x;
    if (e < EE) {
        int dst = edge_index[EE + e];
        int blk = dst >> 4;
        int pos = atomicAdd(&bcnt[blk], 1);
        if (pos < CAP) {
            u32 sl = (u32)(((dst & 15) << 3) | edge_attr[e]);
            bucket[(size_t)blk * CAP + pos] = (u32)edge_index[e] | (sl << 16);
        }
    }
}

// ---------------- one RGCN layer (8 waves; bucket + in-LDS segment ordering) ----------------
// [round-8 verified] Phase A serial-per-segment gather = round-7 body; edge list
// built in-block: 128-entry LDS int counts + 7-round scan + local scatter.
#define RGN 16           // nodes per block; grid = 512

__global__ __launch_bounds__(512) void k_rgcn(const float* __restrict__ xin,
                                              float* __restrict__ xout,
                                              const u16* __restrict__ WTt,    // fragment-tiled
                                              const float* __restrict__ bias, // [H]
                                              const int* __restrict__ bcnt,
                                              const u32* __restrict__ bucket,
                                              float* __restrict__ hGsum) {   // null except L3
    __shared__ u32 ab[RGN * 580];          // 37.1 KB bf16-packed A (row stride 580)
    __shared__ u32 ebuf[CAP];
    __shared__ u16 srcl[CAP];              // segment-ordered src list
    __shared__ int cnt[RGN * RR], incl[RGN * RR], cur[RGN * RR];
    int tid = threadIdx.x, wv = tid >> 6, lane = tid & 63;   // wv 0..7
    int blk = blockIdx.x, n0 = blk * RGN;
    int ne = min(bcnt[blk], CAP);

    for (int i = tid; i < ne; i += 512) ebuf[i] = bucket[(size_t)blk * CAP + i];
    if (tid < RGN * RR) { cnt[tid] = 0; cur[tid] = 0; }
    __syncthreads();
    for (int i = tid; i < ne; i += 512) atomicAdd(&cnt[ebuf[i] >> 16], 1);
    __syncthreads();
    if (tid < RGN * RR) incl[tid] = cnt[tid];
    __syncthreads();
    for (int off = 1; off < RGN * RR; off <<= 1) {   // inclusive scan, 7 rounds
        int v = 0;
        if (tid < RGN * RR && tid >= off) v = incl[tid - off];
        __syncthreads();
        if (tid < RGN * RR) incl[tid] += v;
        __syncthreads();
    }
    for (int i = tid; i < ne; i += 512) {
        int sl = ebuf[i] >> 16;
        int pos = (incl[sl] - cnt[sl]) + atomicAdd(&cur[sl], 1);
        srcl[pos] = (u16)(ebuf[i] & 0xffffu);
    }
    __syncthreads();

    // phase A: wave per segment (16 per wave); lanes cover H via float2
    for (int s = wv; s < RGN * RR; s += 8) {
        int end = incl[s], beg = end - cnt[s];
        float a0 = 0.f, a1 = 0.f;
        for (int e = beg; e < end; ++e) {
            int src = srcl[e];
            float2 v = ((const float2*)(xin + (size_t)src * H))[lane];
            a0 += v.x; a1 += v.y;
        }
        float inv = 1.f / fmaxf((float)(end - beg), 1.f);
        ab[(s >> 3) * 580 + ((s & 7) << 6) + lane] = pk2(a0 * inv, a1 * inv);
    }
    // root block: k-pair slots 512..575
    for (int i = wv; i < RGN; i += 8) {
        const float* xr = xin + (size_t)(n0 + i) * H + 2 * lane;
        ab[i * 580 + 512 + lane] = pk2(xr[0], xr[1]);
    }
    __syncthreads();

    // MFMA GEMM: wave = 16-col tile (tile=wv>>1, sub=wv&1); 36 ksteps 16x16x32
    int m = lane & 15, quad = lane >> 4;
    const u32* aP = ab + m * 580 + quad * 4;
    const u32* bT = (const u32*)WTt + (size_t)(wv >> 1) * 36 * 512 + (wv & 1) * 256 + lane * 4;
    f32x4 acc0 = {0.f, 0.f, 0.f, 0.f};
    bf16x8 b0c = *(const bf16x8*)bT;
    for (int ks = 0; ks < 36; ++ks) {
        bf16x8 b0n;
        if (ks < 35) b0n = *(const bf16x8*)(bT + (ks + 1) * 512);
        bf16x8 a = *(const bf16x8*)(aP + ks * 16);
        acc0 = __builtin_amdgcn_mfma_f32_16x16x32_bf16(a, b0c, acc0, 0, 0, 0);
        b0c = b0n;
    }
    int c0 = wv * 16 + m;
    float bv0 = bias[c0];
    float so0 = 0.f;
#pragma unroll
    for (int rg = 0; rg < 4; ++rg) {
        int n = n0 + quad * 4 + rg;
        float o0 = fmaxf(acc0[rg] + bv0, 0.f);
        xout[(size_t)n * H + c0] = o0;
        so0 += o0;
    }
    if (hGsum) {      // fused mean-pool partial sums (layer 3 only)
        so0 += __shfl_xor(so0, 16, 64);
        so0 += __shfl_xor(so0, 32, 64);
        if (quad == 0) {
            int g = n0 >> 7;
            atomicAdd(&hGsum[g * H + c0], so0);
        }
    }
}

// ---------------- fused action head + sequence pooling (heterogeneous grid) ----------------
__global__ __launch_bounds__(256) void k_pool_seq(const float* __restrict__ hGsum,
                                                  const int* __restrict__ nodes_bs,
                                                  const float* __restrict__ linA_w,
                                                  const float* __restrict__ linA_b,
                                                  const float* __restrict__ linAf_w,
                                                  const float* __restrict__ linAf_b,
                                                  float* __restrict__ hG,
                                                  float* __restrict__ out,
                                                  const float* __restrict__ xf,
                                                  const float* __restrict__ seq,
                                                  const float* __restrict__ emb_actions,
                                                  const int* __restrict__ action_input,
                                                  float* __restrict__ igG) {
    __shared__ float xg[64][H];        // 32 KB (pool part reuses rows 0,1)
    __shared__ u16 lists[LL][64];      // 6 KB
    __shared__ int cnts[LL];
    int tid = threadIdx.x;

    if (blockIdx.x < BB) {
        // ---------------- action head ----------------
        float* hgs = &xg[0][0];
        float* t1  = &xg[1][0];
        int b = blockIdx.x, h = tid;
        if (h < H) {
            float hg = hGsum[(size_t)b * H + h] / (float)nodes_bs[b];
            hG[(size_t)b * H + h] = hg;
            hgs[h] = hg;
        }
        __syncthreads();
        if (h < H) {
            float acc = linA_b[h];
            const float* wr = linA_w + (size_t)h * H;
            for (int k = 0; k < H; ++k) acc += wr[k] * hgs[k];
            t1[h] = fmaxf(acc, 0.f);
        }
        __syncthreads();
        if (h < VA) {
            float a = linAf_b[h];
            const float* w2 = linAf_w + (size_t)h * H;
            for (int k = 0; k < H; ++k) a += w2[k] * t1[k];
            out[(size_t)b * VA + h] = a;
        }
        return;
    }

    // ---------------- sequence pooling -> SHIFTED GRU input igG ----------------
    int b = blockIdx.x - BB;
    int col = tid & 127, tg = tid >> 7;
    float acc[24];
#pragma unroll
    for (int m = 0; m < 24; ++m) acc[m] = 0.f;

    for (int chunk = 0; chunk < 2; ++chunk) {
        int i0 = b * NPG + chunk * 64;
        __syncthreads();
        if (tid < LL) cnts[tid] = 0;
        __syncthreads();
        for (int idx = tid; idx < 64 * H / 4; idx += 256)
            ((float4*)&xg[0][0])[idx] = ((const float4*)(xf + (size_t)i0 * H))[idx];
        for (int idx = tid; idx < 64 * LL; idx += 256) {
            int i = idx / LL, t = idx - i * LL;
            if (seq[(size_t)(i0 + i) * LL + t] != 0.f) {
                int p = atomicAdd(&cnts[t], 1);
                lists[t][p] = (u16)i;
            }
        }
        __syncthreads();
        for (int m = 0; m < 24; ++m) {
            int t = tg + 2 * m;
            int c = cnts[t];
            float a = acc[m];
            for (int p = 0; p < c; ++p) a += xg[lists[t][p]][col];
            acc[m] = a;
        }
    }
    if (tid < H)
        igG[((size_t)b * LL) * H + tid] = emb_actions[(size_t)action_input[b] * H + tid];
#pragma unroll
    for (int m = 0; m < 24; ++m) {
        int t = tg + 2 * m;
        if (t < LL - 1)
            igG[((size_t)b * LL + t + 1) * H + col] = acc[m];
    }
}

// ---------------- xw GEMM -> COALESCED gru layout ----------------
// xw3[gblk][t][wv(8)][gate(3)][quad(4)][mi(16)][4] bf16, pre-scaled for exp2:
//   r,z gates (incl folded b_hh): * log2e;  n gate (b_ih only): * 2*log2e.
__global__ __launch_bounds__(256) void k_xw(const float* __restrict__ igG,
                                            const u16* __restrict__ WTih,
                                            const float* __restrict__ b_ih,
                                            const float* __restrict__ b_hh,
                                            u16* __restrict__ xwG) {
    __shared__ u32 ab[16 * 68];        // 4.35 KB, stride 68
    int tid = threadIdx.x, wv = tid >> 6, lane = tid & 63;
    int n0 = blockIdx.x * 16;
    for (int s = tid; s < 16 * 64; s += 256) {
        int row = s >> 6, kp = s & 63;
        float2 v = *(const float2*)(igG + (size_t)(n0 + row) * H + 2 * kp);
        ab[row * 68 + kp] = pk2(v.x, v.y);
    }
    __syncthreads();
    int m = lane & 15, quad = lane >> 4;
    const u32* aP = ab + m * 68 + quad * 4;
    f32x4 acc[6];
#pragma unroll
    for (int i = 0; i < 6; ++i) acc[i] = (f32x4){0.f, 0.f, 0.f, 0.f};
#pragma unroll
    for (int ks = 0; ks < 4; ++ks) {
        bf16x8 a = *(const bf16x8*)(aP + ks * 16);
#pragma unroll
        for (int tc = 0; tc < 6; ++tc) {
            int colr = wv * 96 + tc * 16 + m;
            bf16x8 bfr = *(const bf16x8*)((const u32*)WTih + (size_t)colr * 64 + quad * 4 + ks * 16);
            acc[tc] = __builtin_amdgcn_mfma_f32_16x16x32_bf16(a, bfr, acc[tc], 0, 0, 0);
        }
    }
#pragma unroll
    for (int tc = 0; tc < 6; ++tc) {
        int c = wv * 96 + tc * 16 + m;
        // fold b_hh for r,z gates; n-gate's b_hh seeds the acc in the gru.
        float bv = b_ih[c] + ((c < 256) ? b_hh[c] : 0.f);
        float sc = (c < 256) ? K_LOG2E : K_2LOG2E;   // exp2 pre-scale
        int R = c & 127, gate = c >> 7;
#pragma unroll
        for (int rg = 0; rg < 4; ++rg) {
            int r = n0 + quad * 4 + rg;
            int bb = r / 48, tt = r - bb * 48;
            size_t o = (((((size_t)(bb >> 4) * LL + tt) * 8 + (R >> 4)) * 3 + gate) * 256)
                     + (((R >> 2) & 3) << 6) + ((bb & 15) << 2) + (R & 3);
            xwG[o] = f2b((acc[tc][rg] + bv) * sc);
        }
    }
}

// ---------------- fused GRU + Bx (heterogeneous grid) ----------------
// Blocks 0..3: batched MFMA GRU (harness-verified body). Blocks 4..259:
// Bx[n,:] = W1b @ x[n] + linN_b (bf16), 32 nodes/block, hidden under GRU.
#define GRU_BLKS 4
#define BX_BLKS  (NN / 32)     // 256
#define SMEM_BYTES 33024       // max(gru 16384, bx 16384+16640)

__global__ __launch_bounds__(512) void k_gru_bx(const u16* __restrict__ xw2,
                                                const float* __restrict__ hG,
                                                const float* __restrict__ w_hh,
                                                const float* __restrict__ b_hh,
                                                const int* __restrict__ len_seq,
                                                float* __restrict__ soutG,
                                                const float* __restrict__ xf,
                                                const float* __restrict__ linN_w,
                                                const float* __restrict__ linN_b,
                                                u16* __restrict__ BxU) {
    __shared__ __align__(16) char smem[SMEM_BYTES];
    int tid = threadIdx.x;

    if (blockIdx.x >= GRU_BLKS) {
        // ---------------- Bx part: 32 nodes, 512 threads ----------------
        float* xl = (float*)smem;                    // [32][128], 16 KB
        float* wb = (float*)(smem + 16384);          // [32][130], 16.6 KB
        int bid = blockIdx.x - GRU_BLKS;
        int n0 = bid * 32;
        for (int idx = tid; idx < 32 * H; idx += 512)
            xl[idx] = xf[(size_t)n0 * H + idx];
        int col = tid & 127, g = tid >> 7;           // g 0..3, 8 nodes each
        float bv = linN_b[col];
        float acc[8] = {bv, bv, bv, bv, bv, bv, bv, bv};
        for (int c = 0; c < 4; ++c) {
            int k0 = c * 32;
            __syncthreads();
            for (int idx = tid; idx < 32 * H; idx += 512) {
                int r = idx >> 5, kk = idx & 31;
                wb[kk * 130 + r] = linN_w[(size_t)r * (2 * H) + H + k0 + kk];
            }
            __syncthreads();
#pragma unroll
            for (int kk = 0; kk < 32; ++kk) {
                float w = wb[kk * 130 + col];
#pragma unroll
                for (int j = 0; j < 8; ++j) acc[j] += xl[(g * 8 + j) * H + k0 + kk] * w;
            }
        }
#pragma unroll
        for (int j = 0; j < 8; ++j)
            BxU[(size_t)(n0 + g * 8 + j) * H + col] = f2b(acc[j]);
        return;
    }

    // ---------------- GRU part ----------------
    u16* hA = (u16*)smem;    // [2][2][2048]: (buf*2+hl)*2048 + e, 16 KB
    int lane = tid & 63, wv = tid >> 6;       // wv 0..7
    int mi = lane & 15, quad = lane >> 4;     // mi = graph col
    int gblk = blockIdx.x;
    int g_abs = gblk * GPB + mi;
    int R0 = 16 * wv + 4 * quad;              // this lane's 4 h-rows [R0, R0+4)

    // fragment-order write slot for rows R0..R0+3 of graph mi:
    //   row R -> (ks=R>>5, lane'=mi+16*((R>>3)&3), j=R&7); reg r=0..3 -> j0+r.
    int eW = (((wv >> 1) * 64) + (mi + 16 * ((2 * wv + (quad >> 1)) & 3))) * 8
             + 4 * (quad & 1);

    // W_hh A-fragments, register-resident: 3 tiles (r,z,n), 4 ks each = 48 VGPR.
    // Pre-scaled: r,z by log2e; n by 2*log2e (exact, folded into bf16 quantize).
    bf16x8 wfr[3][4];
#pragma unroll
    for (int gate = 0; gate < 3; ++gate) {
        int T = wv + 8 * gate;
        float sc = (gate == 2) ? K_2LOG2E : K_LOG2E;
#pragma unroll
        for (int ks = 0; ks < 4; ++ks) {
            const float* wp = w_hh + (size_t)(16 * T + mi) * H + quad * 8 + ks * 32;
            float4 f0 = *(const float4*)wp;
            float4 f1 = *(const float4*)(wp + 4);
            bf16x8 v;
            v[0] = (short)f2b(f0.x * sc); v[1] = (short)f2b(f0.y * sc);
            v[2] = (short)f2b(f0.z * sc); v[3] = (short)f2b(f0.w * sc);
            v[4] = (short)f2b(f1.x * sc); v[5] = (short)f2b(f1.y * sc);
            v[6] = (short)f2b(f1.z * sc); v[7] = (short)f2b(f1.w * sc);
            wfr[gate][ks] = v;
        }
    }
    float4 bn = *(const float4*)(b_hh + 256 + R0);     // n-gate bias (acc seed)
    float4 h0 = *(const float4*)(hG + (size_t)g_abs * H + R0);
    int ls = len_seq[g_abs];

    float hp[4]  = {h0.x, h0.y, h0.z, h0.w};
    float bnn[4] = {bn.x * K_2LOG2E, bn.y * K_2LOG2E, bn.z * K_2LOG2E, bn.w * K_2LOG2E};

    auto storeh = [&](int buf, const float* hv) {
        u32 w0 = cvtpk(hv[0], hv[1]);
        u32 w1 = cvtpk(hv[2], hv[3]);
        float2 e0 = up2(w0), e1 = up2(w1);
        u32 l0 = cvtpk(hv[0] - e0.x, hv[1] - e0.y);    // hi+lo: ~17-bit h mantissa
        u32 l1 = cvtpk(hv[2] - e1.x, hv[3] - e1.y);
        *(uint2*)&hA[buf * 4096 + eW]        = make_uint2(w0, w1);
        *(uint2*)&hA[buf * 4096 + 2048 + eW] = make_uint2(l0, l1);
    };
    auto loadxw = [&](int t, u16x4* d) {
        const u16* p = xw2 + ((((size_t)gblk * LL + t) * 8 + wv) * 3) * 256
                     + (quad << 6) + (mi << 2);
        d[0] = *(const u16x4*)(p);          // r   (512B coalesced per wave)
        d[1] = *(const u16x4*)(p + 256);    // z
        d[2] = *(const u16x4*)(p + 512);    // n
    };

    auto step = [&](int t, const u16x4* x, int buf) {
        f32x4 acc[3];
        acc[0] = (f32x4){0.f, 0.f, 0.f, 0.f};
        acc[1] = (f32x4){0.f, 0.f, 0.f, 0.f};
        acc[2] = (f32x4){bnn[0], bnn[1], bnn[2], bnn[3]};
#pragma unroll
        for (int ks = 0; ks < 4; ++ks) {
            const int e = (ks * 64 + lane) * 8;           // own 16B, conflict-free
            bf16x8 bh = *(const bf16x8*)&hA[buf * 4096 + e];
            bf16x8 bl = *(const bf16x8*)&hA[buf * 4096 + 2048 + e];
#pragma unroll
            for (int gate = 0; gate < 3; ++gate) {
                acc[gate] = __builtin_amdgcn_mfma_f32_16x16x32_bf16(wfr[gate][ks], bh, acc[gate], 0, 0, 0);
                acc[gate] = __builtin_amdgcn_mfma_f32_16x16x32_bf16(wfr[gate][ks], bl, acc[gate], 0, 0, 0);
            }
        }
        float hv[4];
        float4 so;
#pragma unroll
        for (int r = 0; r < 4; ++r) {
            float xr = b2f(x[0][r]);                      // pre-scaled by log2e
            float xz = b2f(x[1][r]);
            float xn = b2f(x[2][r]);                      // pre-scaled by 2log2e
            float rg = rcpf(1.f + __builtin_amdgcn_exp2f(-(xr + acc[0][r])));
            float zg = rcpf(1.f + __builtin_amdgcn_exp2f(-(xz + acc[1][r])));
            float u  = xn + rg * acc[2][r];               // = 2*log2e*(true u)
            float ng = 1.f - 2.f * rcpf(__builtin_amdgcn_exp2f(u) + 1.f);
            float hn = ng + zg * (hp[r] - ng);
            hp[r] = hn;
            hv[r] = hn;
            ((float*)&so)[r] = (t < ls) ? hn : 0.f;       // pad_packed mask
        }
        *(float4*)(soutG + ((size_t)g_abs * LL + t) * H + R0) = so;
        storeh(buf ^ 1, hv);
    };

    u16x4 xa[3], xb[3];
    loadxw(0, xa);
    loadxw(1, xb);
    storeh(0, hp);
    asm volatile("s_waitcnt lgkmcnt(0)\n\ts_barrier" ::: "memory");

    for (int t = 0; t < LL; t += 2) {
        step(t, xa, 0);
        if (t + 2 < LL) loadxw(t + 2, xa);
        // LDS-only barrier: do NOT drain vmcnt (stores/prefetch stay in flight)
        asm volatile("s_waitcnt lgkmcnt(0)\n\ts_barrier" ::: "memory");
        step(t + 1, xb, 1);
        if (t + 3 < LL) loadxw(t + 3, xb);
        asm volatile("s_waitcnt lgkmcnt(0)\n\ts_barrier" ::: "memory");
    }
}

// ---------------- A2[row,:] = W1a @ sout[row]  (rows = b*48+t), f32 out ----------------
__global__ __launch_bounds__(256) void k_a2(const float* __restrict__ soutG,
                                            const float* __restrict__ linN_w,
                                            float* __restrict__ A2) {
    __shared__ float wb[32][130];
    __shared__ float xl[16][H];
    int tid = threadIdx.x;
    int n0 = blockIdx.x * 16;
    for (int idx = tid; idx < 16 * H; idx += 256)
        xl[idx >> 7][idx & 127] = soutG[(size_t)n0 * H + idx];
    int col = tid & 127, g = tid >> 7;
    float acc[8] = {0.f, 0.f, 0.f, 0.f, 0.f, 0.f, 0.f, 0.f};
    for (int c = 0; c < 4; ++c) {
        int k0 = c * 32;
        __syncthreads();
        for (int idx = tid; idx < 32 * H; idx += 256) {
            int r = idx >> 5, kk = idx & 31;
            wb[kk][r] = linN_w[(size_t)r * (2 * H) + k0 + kk];
        }
        __syncthreads();
#pragma unroll
        for (int kk = 0; kk < 32; ++kk) {
            float w = wb[kk][col];
#pragma unroll
            for (int j = 0; j < 8; ++j) acc[j] += xl[g * 8 + j][k0 + kk] * w;
        }
    }
#pragma unroll
    for (int j = 0; j < 8; ++j)
        A2[(size_t)(n0 + g * 8 + j) * H + col] = acc[j];
}

// ---------------- logits[n][t] = sum_k w2[k]*relu(A2[t][k]+Bx[n][k]) ----------------
__global__ __launch_bounds__(256) void k_logits(const float* __restrict__ A2,
                                                const u16* __restrict__ BxU,
                                                const float* __restrict__ linNf_w,
                                                float* __restrict__ logits) {
    __shared__ float a2s[LL][130];
    __shared__ float bxs[16][130];
    __shared__ float w2s[H];
    int tid = threadIdx.x;
    int g = blockIdx.x >> 3, tile = blockIdx.x & 7;
    int n0g = g * NPG + tile * 16;

    for (int i2 = tid; i2 < LL * 64; i2 += 256) {
        int r = i2 >> 6, c2 = i2 & 63;
        *(float2*)&a2s[r][2 * c2] = *(const float2*)(A2 + ((size_t)g * LL + r) * H + 2 * c2);
    }
    for (int iu = tid; iu < 16 * 64; iu += 256) {
        int r = iu >> 6, c = iu & 63;
        float2 v = up2(((const u32*)BxU)[(size_t)(n0g + r) * 64 + c]);
        *(float2*)&bxs[r][2 * c] = v;
    }
    if (tid < H) w2s[tid] = linNf_w[tid];
    __syncthreads();

    int n = tid & 15, tt = tid >> 4;
#pragma unroll
    for (int pass = 0; pass < 3; ++pass) {
        int t = tt + 16 * pass;
        float acc = 0.f;
#pragma unroll
        for (int kp = 0; kp < 64; ++kp) {
            float2 a2 = *(const float2*)&a2s[t][2 * kp];
            float2 bx = *(const float2*)&bxs[n][2 * kp];
            float2 w  = *(const float2*)&w2s[2 * kp];
            acc += w.x * fmaxf(a2.x + bx.x, 0.f) + w.y * fmaxf(a2.y + bx.y, 0.f);
        }
        logits[(size_t)(n0g + n) * LL + t] = acc;
    }
}

// ---------------- per-(graph,t) softmax over nodes; write output ----------------
__global__ __launch_bounds__(256) void k_softmax(const float* __restrict__ logits,
                                                 float* __restrict__ out) {
    __shared__ float lg[NPG][LL + 1];
    __shared__ float pm[4][LL], ps[4][LL];
    __shared__ float mv[LL], inv[LL];
    int b = blockIdx.x, tid = threadIdx.x;
    int n0 = b * NPG;
    for (int idx = tid; idx < NPG * LL; idx += 256) {
        int n = idx / LL, t = idx - n * LL;
        lg[n][t] = logits[(size_t)n0 * LL + idx];
    }
    __syncthreads();
    int t = tid & 63, seg = tid >> 6;
    if (t < LL) {
        float m = -1e30f;
        int nb = seg * 32;
        for (int n = nb; n < nb + 32; ++n) m = fmaxf(m, lg[n][t]);
        pm[seg][t] = m;
    }
    __syncthreads();
    if (tid < LL)
        mv[tid] = fmaxf(fmaxf(pm[0][tid], pm[1][tid]), fmaxf(pm[2][tid], pm[3][tid]));
    __syncthreads();
    if (t < LL) {
        float m = mv[t], s = 0.f;
        int nb = seg * 32;
        for (int n = nb; n < nb + 32; ++n) {
            float e = __expf(lg[n][t] - m);
            lg[n][t] = e;
            s += e;
        }
        ps[seg][t] = s;
    }
    __syncthreads();
    if (tid < LL)
        inv[tid] = 1.f / (ps[0][tid] + ps[1][tid] + ps[2][tid] + ps[3][tid]);
    __syncthreads();
    for (int idx = tid; idx < NPG * LL; idx += 256) {
        int n = idx / LL, tc = idx - n * LL;
        out[(size_t)BB * VA + (size_t)n0 * LL + idx] = lg[n][tc] * inv[tc];
    }
}

// ---------------- launch ----------------
extern "C" void kernel_launch(void* const* d_in, const int* in_sizes, int n_in,
                              void* d_out, int out_size, void* d_ws, size_t ws_size,
                              hipStream_t stream) {
    (void)in_sizes; (void)n_in; (void)out_size; (void)ws_size;
    const int*   nodeTypes    = (const int*)d_in[0];
    const int*   edge_index   = (const int*)d_in[1];
    const int*   edge_attr    = (const int*)d_in[2];
    const int*   nodes_bs     = (const int*)d_in[4];
    const int*   len_seq      = (const int*)d_in[5];
    const float* seq_in       = (const float*)d_in[6];
    const int*   action_input = (const int*)d_in[7];
    const float* emb_nodes    = (const float*)d_in[8];
    const float* emb_actions  = (const float*)d_in[9];
    const float* rgcn_rel     = (const float*)d_in[10];
    const float* rgcn_root    = (const float*)d_in[11];
    const float* rgcn_bias    = (const float*)d_in[12];
    const float* gru_w_ih     = (const float*)d_in[13];
    const float* gru_w_hh     = (const float*)d_in[14];
    const float* gru_b_ih     = (const float*)d_in[15];
    const float* gru_b_hh     = (const float*)d_in[16];
    const float* linA_w       = (const float*)d_in[17];
    const float* linA_b       = (const float*)d_in[18];
    const float* linAf_w      = (const float*)d_in[19];
    const float* linAf_b      = (const float*)d_in[20];
    const float* linN_w       = (const float*)d_in[21];
    const float* linN_b       = (const float*)d_in[22];
    const float* linNf_w      = (const float*)d_in[23];
    // linNf_b cancels in the softmax

    char* w = (char*)d_ws;
    float* x0      = (float*)(w + 0);          // [0,4MB) emb ping; dead after rgcn L3
    u16*   xwG     = (u16*)  (w + 0);          //   overlay (after L3): [0, 2,359,296)
    float* logitsW = (float*)(w + 0);          //   overlay (after k_gru_bx): [0, 1,572,864)
    float* soutG   = (float*)(w + 2359296);    //   overlay (after L3): [.., 3,932,160)
    float* x1      = (float*)(w + 4194304);    // [4MB,8MB) final x f32 (live to end)
    float* igG     = (float*)(w + 8388608);    // [8MB, 9,961,472) shifted GRU input
    float* A2      = (float*)(w + 8388608);    //   overlay (igG dead before k_a2)
    u16*   BxU     = (u16*)  (w + 9961472);    // [9,961,472, 12,058,624)
    float* hGsum   = (float*)(w + 9969664);    //   overlay on BxU + 8 KB (dead by k_gru_bx)
    int*   bcnt    = (int*)  (w + 11567104);   //   overlay on BxU tail (dead by k_gru_bx), 2 KB
    u16*   WTih    = (u16*)  (w + 11829760);   //   overlay on BxU tail (dead after k_xw)
    float* hG      = (float*)(w + 12058624);   // 32 KB
    u32*   bucket  = (u32*)  (w + 12091904);   // 512 KB = 512 blocks x CAP x 4B; dead after L3
    u16*   WT      = (u16*)  (w + 12616192);   // rgcn weights bf16 (tiled), 884,736 B

    float* out_f = (float*)d_out;

    k_prep<<<dim3(5824), dim3(256), 0, stream>>>(nodeTypes, emb_nodes, rgcn_rel,
        rgcn_root, gru_w_ih, x0, WT, WTih, hGsum, bcnt);
    k_bucket<<<dim3(256), dim3(256), 0, stream>>>(edge_index, edge_attr, bcnt, bucket);

    const int rg_grid = NN / RGN;   // 512
    k_rgcn<<<dim3(rg_grid), dim3(512), 0, stream>>>(x0, x1,
        WT + 0 * 147456, rgcn_bias + 0 * H, bcnt, bucket, nullptr);
    k_rgcn<<<dim3(rg_grid), dim3(512), 0, stream>>>(x1, x0,
        WT + 1 * 147456, rgcn_bias + 1 * H, bcnt, bucket, nullptr);
    k_rgcn<<<dim3(rg_grid), dim3(512), 0, stream>>>(x0, x1,
        WT + 2 * 147456, rgcn_bias + 2 * H, bcnt, bucket, hGsum);
    // x_final = x1 (x0 region free from here)

    k_pool_seq<<<dim3(2 * BB), dim3(256), 0, stream>>>(hGsum, nodes_bs, linA_w, linA_b,
        linAf_w, linAf_b, hG, out_f, x1, seq_in, emb_actions, action_input, igG);
    k_xw<<<dim3(BB * LL / 16), dim3(256), 0, stream>>>(igG, WTih, gru_b_ih, gru_b_hh, xwG);
    k_gru_bx<<<dim3(GRU_BLKS + BX_BLKS), dim3(512), 0, stream>>>(xwG, hG, gru_w_hh,
        gru_b_hh, len_seq, soutG, x1, linN_w, linN_b, BxU);
    k_a2<<<dim3(BB * LL / 16), dim3(256), 0, stream>>>(soutG, linN_w, A2);
    k_logits<<<dim3(BB * 8), dim3(256), 0, stream>>>(A2, BxU, linNf_w, logitsW);
    k_softmax<<<dim3(BB), dim3(256), 0, stream>>>(logitsW, out_f);
}

// Round 10
// 308.502 us; speedup vs baseline: 1.2727x; 1.0407x over previous
//
#include <hip/hip_runtime.h>
#include <hip/hip_bf16.h>

#define H   128
#define RR  8
#define NN  8192
#define BB  64
#define LL  48
#define EE  65536
#define NPG 128          // nodes per graph (N/B)
#define VA  64
#define NSEG (NN*RR)     // 65536
#define GPB 16           // graphs per block in gru part

typedef unsigned short u16;
typedef unsigned int   u32;

__device__ __forceinline__ float b2f(u16 u) {
    union { u32 i; float f; } v; v.i = ((u32)u) << 16; return v.f;
}
__device__ __forceinline__ u16 f2b(float f) {
    union { float f; u32 i; } v; v.f = f;
    u32 x = v.i;
    return (u16)((x + 0x7fffu + ((x >> 16) & 1u)) >> 16);
}
__device__ __forceinline__ float2 up2(u32 p) {
    union { u32 i; float f; } a, b;
    a.i = p << 16; b.i = p & 0xffff0000u;
    return make_float2(a.f, b.f);
}
__device__ __forceinline__ u32 pk2(float a, float b) {
    return ((u32)f2b(b) << 16) | (u32)f2b(a);
}
__device__ __forceinline__ float rcpf(float x) { return __builtin_amdgcn_rcpf(x); }
__device__ __forceinline__ u32 cvtpk(float lo, float hi) {   // dst={hi16:cvt(hi), lo16:cvt(lo)}
    u32 r;
    asm("v_cvt_pk_bf16_f32 %0, %1, %2" : "=v"(r) : "v"(lo), "v"(hi));
    return r;
}

#define K_LOG2E  1.4426950408889634f
#define K_2LOG2E 2.8853900817779268f

typedef __attribute__((ext_vector_type(8))) short bf16x8;
typedef __attribute__((ext_vector_type(4))) float f32x4;
typedef __attribute__((ext_vector_type(4))) unsigned short u16x4;

// ---------------- fused prep: zero seg counters + embed nodes + weight tiling ----------------
__global__ __launch_bounds__(256) void k_prep(const int* __restrict__ nodeTypes,
                                              const float* __restrict__ emb_nodes,
                                              const float* __restrict__ rel,
                                              const float* __restrict__ root,
                                              const float* __restrict__ w_ih,
                                              float* __restrict__ x0,
                                              u16* __restrict__ WTt,
                                              u16* __restrict__ WTih,
                                              float* __restrict__ hGsum,
                                              int* __restrict__ fill) {
    int idx = blockIdx.x * 256 + threadIdx.x;
    if (idx < NSEG) fill[idx] = 0;
    if (idx < 384 * H) WTih[idx] = f2b(w_ih[idx]);
    if (idx < BB * H) hGsum[idx] = 0.f;
    if (idx < NN * H) {
        int n = idx >> 7, h = idx & (H - 1);
        x0[idx] = emb_nodes[(size_t)nodeTypes[n] * H + h];
    }
    int j = idx - NN * H;
    if (j < 0 || j >= 3 * 147456) return;
    int li  = j / 147456;
    int rem = j - li * 147456;
    int tile = rem / 36864;
    int r2   = rem - tile * 36864;
    int ks   = r2 / 1024;
    int r3   = r2 - ks * 1024;
    int sub  = r3 >> 9;
    int r4   = r3 & 511;
    int lane = r4 >> 3, jj = r4 & 7;
    int col = tile * 32 + sub * 16 + (lane & 15);
    int k   = ks * 32 + (lane >> 4) * 8 + jj;
    float v;
    if (k < 1024) v = rel[(((size_t)li * RR + (k >> 7)) * H + (k & 127)) * H + col];
    else          v = root[((size_t)li * H + (k - 1024)) * H + col];
    WTt[j] = f2b(v);
}

// ---------------- histogram of (dst,rel) segments ----------------
__global__ __launch_bounds__(256) void k_hist(const int* __restrict__ edge_index,
                                              const int* __restrict__ edge_attr,
                                              int* __restrict__ fill) {
    int e = blockIdx.x * 256 + threadIdx.x;
    if (e < EE) {
        int seg = edge_index[EE + e] * RR + edge_attr[e];
        atomicAdd(&fill[seg], 1);
    }
}

// ---------------- scan stage 1: per-256-chunk sums ----------------
__global__ __launch_bounds__(256) void k_scan1(const int* __restrict__ fill,
                                               int* __restrict__ bsum) {
    __shared__ int red[4];
    int tid = threadIdx.x, lane = tid & 63, wv = tid >> 6;
    int v = fill[blockIdx.x * 256 + tid];
#pragma unroll
    for (int off = 32; off >= 1; off >>= 1) v += __shfl_down(v, off, 64);
    if (lane == 0) red[wv] = v;
    __syncthreads();
    if (tid == 0) bsum[blockIdx.x] = red[0] + red[1] + red[2] + red[3];
}

// ---------------- scan stage 2+3 merged: each block re-scans bsum (replaces the
// 1-block k_scan2 launch) alongside its local fill scan -> rowptr ----------------
__global__ __launch_bounds__(256) void k_scan3(const int* __restrict__ bsum,
                                               int* __restrict__ fill,
                                               int* __restrict__ rowptr) {
    __shared__ int s[256], s2[256];
    __shared__ int boffs;
    int tid = threadIdx.x;
    int g = blockIdx.x * 256 + tid;
    int c = fill[g];
    int b0 = bsum[tid];
    s[tid] = c;
    s2[tid] = b0;
    __syncthreads();
    for (int off = 1; off < 256; off <<= 1) {
        int v  = (tid >= off) ? s[tid - off]  : 0;
        int v2 = (tid >= off) ? s2[tid - off] : 0;
        __syncthreads();
        s[tid] += v;
        s2[tid] += v2;
        __syncthreads();
    }
    if (blockIdx.x == 0 && tid == 255) rowptr[NSEG] = s2[255];
    if (tid == blockIdx.x) boffs = s2[tid] - b0;   // exclusive block offset
    __syncthreads();
    int r = boffs + s[tid] - c;
    rowptr[g] = r;
    fill[g] = r;    // becomes scatter cursor
}

// ---------------- scatter edges into CSR ----------------
__global__ __launch_bounds__(256) void k_scatter(const int* __restrict__ edge_index,
                                                 const int* __restrict__ edge_attr,
                                                 int* __restrict__ fill,
                                                 int* __restrict__ colidx) {
    int e = blockIdx.x * 256 + threadIdx.x;
    if (e < EE) {
        int seg = edge_index[EE + e] * RR + edge_attr[e];
        int pos = atomicAdd(&fill[seg], 1);
        colidx[pos] = edge_index[e];   // src
    }
}

// ---------------- one RGCN layer (8 waves, CSR gather; round-7 verified) ----------------
#define RGN 16           // nodes per block; grid = 512
#define EPRE 512

__global__ __launch_bounds__(512) void k_rgcn(const float* __restrict__ xin,
                                              float* __restrict__ xout,
                                              const u16* __restrict__ WTt,    // fragment-tiled
                                              const float* __restrict__ bias, // [H]
                                              const int* __restrict__ rowptr,
                                              const int* __restrict__ colidx,
                                              float* __restrict__ hGsum) {   // null except L3
    __shared__ u32 ab[RGN * 580];          // 37.1 KB bf16-packed A (row stride 580)
    __shared__ int begs[RGN * RR + 1];
    __shared__ int eidx[EPRE];
    int tid = threadIdx.x, wv = tid >> 6, lane = tid & 63;   // wv 0..7
    int n0 = blockIdx.x * RGN, segbase = n0 * RR;

    if (tid <= RGN * RR) begs[tid] = rowptr[segbase + tid];
    __syncthreads();
    int E0 = begs[0], ne = begs[RGN * RR] - E0;
    for (int i = tid; i < ne && i < EPRE; i += 512) eidx[i] = colidx[E0 + i];
    __syncthreads();

    // phase A: wave per segment (16 per wave); lanes cover H via float2
    for (int s = wv; s < RGN * RR; s += 8) {
        int beg = begs[s], end = begs[s + 1];
        float a0 = 0.f, a1 = 0.f;
        for (int e = beg; e < end; ++e) {
            int off = e - E0;
            int src = (off < EPRE) ? eidx[off] : colidx[e];
            float2 v = ((const float2*)(xin + (size_t)src * H))[lane];
            a0 += v.x; a1 += v.y;
        }
        float inv = 1.f / fmaxf((float)(end - beg), 1.f);
        ab[(s >> 3) * 580 + ((s & 7) << 6) + lane] = pk2(a0 * inv, a1 * inv);
    }
    // root block: k-pair slots 512..575
    for (int i = wv; i < RGN; i += 8) {
        const float* xr = xin + (size_t)(n0 + i) * H + 2 * lane;
        ab[i * 580 + 512 + lane] = pk2(xr[0], xr[1]);
    }
    __syncthreads();

    // MFMA GEMM: wave = 16-col tile (tile=wv>>1, sub=wv&1); 36 ksteps 16x16x32
    int m = lane & 15, quad = lane >> 4;
    const u32* aP = ab + m * 580 + quad * 4;
    const u32* bT = (const u32*)WTt + (size_t)(wv >> 1) * 36 * 512 + (wv & 1) * 256 + lane * 4;
    f32x4 acc0 = {0.f, 0.f, 0.f, 0.f};
    bf16x8 b0c = *(const bf16x8*)bT;
    for (int ks = 0; ks < 36; ++ks) {
        bf16x8 b0n;
        if (ks < 35) b0n = *(const bf16x8*)(bT + (ks + 1) * 512);
        bf16x8 a = *(const bf16x8*)(aP + ks * 16);
        acc0 = __builtin_amdgcn_mfma_f32_16x16x32_bf16(a, b0c, acc0, 0, 0, 0);
        b0c = b0n;
    }
    int c0 = wv * 16 + m;
    float bv0 = bias[c0];
    float so0 = 0.f;
#pragma unroll
    for (int rg = 0; rg < 4; ++rg) {
        int n = n0 + quad * 4 + rg;
        float o0 = fmaxf(acc0[rg] + bv0, 0.f);
        xout[(size_t)n * H + c0] = o0;
        so0 += o0;
    }
    if (hGsum) {      // fused mean-pool partial sums (layer 3 only)
        so0 += __shfl_xor(so0, 16, 64);
        so0 += __shfl_xor(so0, 32, 64);
        if (quad == 0) {
            int g = n0 >> 7;
            atomicAdd(&hGsum[g * H + c0], so0);
        }
    }
}

// ---------------- fused action head + sequence pooling (heterogeneous grid) ----------------
__global__ __launch_bounds__(256) void k_pool_seq(const float* __restrict__ hGsum,
                                                  const int* __restrict__ nodes_bs,
                                                  const float* __restrict__ linA_w,
                                                  const float* __restrict__ linA_b,
                                                  const float* __restrict__ linAf_w,
                                                  const float* __restrict__ linAf_b,
                                                  float* __restrict__ hG,
                                                  float* __restrict__ out,
                                                  const float* __restrict__ xf,
                                                  const float* __restrict__ seq,
                                                  const float* __restrict__ emb_actions,
                                                  const int* __restrict__ action_input,
                                                  float* __restrict__ igG) {
    __shared__ float xg[64][H];        // 32 KB (pool part reuses rows 0,1)
    __shared__ u16 lists[LL][64];      // 6 KB
    __shared__ int cnts[LL];
    int tid = threadIdx.x;

    if (blockIdx.x < BB) {
        // ---------------- action head ----------------
        float* hgs = &xg[0][0];
        float* t1  = &xg[1][0];
        int b = blockIdx.x, h = tid;
        if (h < H) {
            float hg = hGsum[(size_t)b * H + h] / (float)nodes_bs[b];
            hG[(size_t)b * H + h] = hg;
            hgs[h] = hg;
        }
        __syncthreads();
        if (h < H) {
            float acc = linA_b[h];
            const float* wr = linA_w + (size_t)h * H;
            for (int k = 0; k < H; ++k) acc += wr[k] * hgs[k];
            t1[h] = fmaxf(acc, 0.f);
        }
        __syncthreads();
        if (h < VA) {
            float a = linAf_b[h];
            const float* w2 = linAf_w + (size_t)h * H;
            for (int k = 0; k < H; ++k) a += w2[k] * t1[k];
            out[(size_t)b * VA + h] = a;
        }
        return;
    }

    // ---------------- sequence pooling -> SHIFTED GRU input igG ----------------
    int b = blockIdx.x - BB;
    int col = tid & 127, tg = tid >> 7;
    float acc[24];
#pragma unroll
    for (int m = 0; m < 24; ++m) acc[m] = 0.f;

    for (int chunk = 0; chunk < 2; ++chunk) {
        int i0 = b * NPG + chunk * 64;
        __syncthreads();
        if (tid < LL) cnts[tid] = 0;
        __syncthreads();
        for (int idx = tid; idx < 64 * H / 4; idx += 256)
            ((float4*)&xg[0][0])[idx] = ((const float4*)(xf + (size_t)i0 * H))[idx];
        for (int idx = tid; idx < 64 * LL; idx += 256) {
            int i = idx / LL, t = idx - i * LL;
            if (seq[(size_t)(i0 + i) * LL + t] != 0.f) {
                int p = atomicAdd(&cnts[t], 1);
                lists[t][p] = (u16)i;
            }
        }
        __syncthreads();
        for (int m = 0; m < 24; ++m) {
            int t = tg + 2 * m;
            int c = cnts[t];
            float a = acc[m];
            for (int p = 0; p < c; ++p) a += xg[lists[t][p]][col];
            acc[m] = a;
        }
    }
    if (tid < H)
        igG[((size_t)b * LL) * H + tid] = emb_actions[(size_t)action_input[b] * H + tid];
#pragma unroll
    for (int m = 0; m < 24; ++m) {
        int t = tg + 2 * m;
        if (t < LL - 1)
            igG[((size_t)b * LL + t + 1) * H + col] = acc[m];
    }
}

// ---------------- xw GEMM -> COALESCED gru layout ----------------
// xw3[gblk][t][wv(8)][gate(3)][quad(4)][mi(16)][4] bf16, pre-scaled for exp2:
//   r,z gates (incl folded b_hh): * log2e;  n gate (b_ih only): * 2*log2e.
__global__ __launch_bounds__(256) void k_xw(const float* __restrict__ igG,
                                            const u16* __restrict__ WTih,
                                            const float* __restrict__ b_ih,
                                            const float* __restrict__ b_hh,
                                            u16* __restrict__ xwG) {
    __shared__ u32 ab[16 * 68];        // 4.35 KB, stride 68
    int tid = threadIdx.x, wv = tid >> 6, lane = tid & 63;
    int n0 = blockIdx.x * 16;
    for (int s = tid; s < 16 * 64; s += 256) {
        int row = s >> 6, kp = s & 63;
        float2 v = *(const float2*)(igG + (size_t)(n0 + row) * H + 2 * kp);
        ab[row * 68 + kp] = pk2(v.x, v.y);
    }
    __syncthreads();
    int m = lane & 15, quad = lane >> 4;
    const u32* aP = ab + m * 68 + quad * 4;
    f32x4 acc[6];
#pragma unroll
    for (int i = 0; i < 6; ++i) acc[i] = (f32x4){0.f, 0.f, 0.f, 0.f};
#pragma unroll
    for (int ks = 0; ks < 4; ++ks) {
        bf16x8 a = *(const bf16x8*)(aP + ks * 16);
#pragma unroll
        for (int tc = 0; tc < 6; ++tc) {
            int colr = wv * 96 + tc * 16 + m;
            bf16x8 bfr = *(const bf16x8*)((const u32*)WTih + (size_t)colr * 64 + quad * 4 + ks * 16);
            acc[tc] = __builtin_amdgcn_mfma_f32_16x16x32_bf16(a, bfr, acc[tc], 0, 0, 0);
        }
    }
#pragma unroll
    for (int tc = 0; tc < 6; ++tc) {
        int c = wv * 96 + tc * 16 + m;
        // fold b_hh for r,z gates; n-gate's b_hh seeds the acc in the gru.
        float bv = b_ih[c] + ((c < 256) ? b_hh[c] : 0.f);
        float sc = (c < 256) ? K_LOG2E : K_2LOG2E;   // exp2 pre-scale
        int R = c & 127, gate = c >> 7;
#pragma unroll
        for (int rg = 0; rg < 4; ++rg) {
            int r = n0 + quad * 4 + rg;
            int bb = r / 48, tt = r - bb * 48;
            size_t o = (((((size_t)(bb >> 4) * LL + tt) * 8 + (R >> 4)) * 3 + gate) * 256)
                     + (((R >> 2) & 3) << 6) + ((bb & 15) << 2) + (R & 3);
            xwG[o] = f2b((acc[tc][rg] + bv) * sc);
        }
    }
}

// ---------------- fused GRU + Bx (heterogeneous grid) ----------------
// Blocks 0..3: batched MFMA GRU. v5: single-bf16 h (hi/lo split dropped) —
// owner-lane recurrence hp[] stays f32 (rounding doesn't compound); only the
// matvec operand is bf16. MFMA 24->12/step, chain 8->4/gate, storeh halved.
// Blocks 4..259: Bx[n,:] = W1b @ x[n] + linN_b (bf16), hidden under GRU.
#define GRU_BLKS 4
#define BX_BLKS  (NN / 32)     // 256
#define SMEM_BYTES 33024       // max(gru 8192, bx 16384+16640)

__global__ __launch_bounds__(512) void k_gru_bx(const u16* __restrict__ xw2,
                                                const float* __restrict__ hG,
                                                const float* __restrict__ w_hh,
                                                const float* __restrict__ b_hh,
                                                const int* __restrict__ len_seq,
                                                float* __restrict__ soutG,
                                                const float* __restrict__ xf,
                                                const float* __restrict__ linN_w,
                                                const float* __restrict__ linN_b,
                                                u16* __restrict__ BxU) {
    __shared__ __align__(16) char smem[SMEM_BYTES];
    int tid = threadIdx.x;

    if (blockIdx.x >= GRU_BLKS) {
        // ---------------- Bx part: 32 nodes, 512 threads ----------------
        float* xl = (float*)smem;                    // [32][128], 16 KB
        float* wb = (float*)(smem + 16384);          // [32][130], 16.6 KB
        int bid = blockIdx.x - GRU_BLKS;
        int n0 = bid * 32;
        for (int idx = tid; idx < 32 * H; idx += 512)
            xl[idx] = xf[(size_t)n0 * H + idx];
        int col = tid & 127, g = tid >> 7;           // g 0..3, 8 nodes each
        float bv = linN_b[col];
        float acc[8] = {bv, bv, bv, bv, bv, bv, bv, bv};
        for (int c = 0; c < 4; ++c) {
            int k0 = c * 32;
            __syncthreads();
            for (int idx = tid; idx < 32 * H; idx += 512) {
                int r = idx >> 5, kk = idx & 31;
                wb[kk * 130 + r] = linN_w[(size_t)r * (2 * H) + H + k0 + kk];
            }
            __syncthreads();
#pragma unroll
            for (int kk = 0; kk < 32; ++kk) {
                float w = wb[kk * 130 + col];
#pragma unroll
                for (int j = 0; j < 8; ++j) acc[j] += xl[(g * 8 + j) * H + k0 + kk] * w;
            }
        }
#pragma unroll
        for (int j = 0; j < 8; ++j)
            BxU[(size_t)(n0 + g * 8 + j) * H + col] = f2b(acc[j]);
        return;
    }

    // ---------------- GRU part ----------------
    u16* hA = (u16*)smem;    // [2][2048]: buf*2048 + e, 8 KB
    int lane = tid & 63, wv = tid >> 6;       // wv 0..7
    int mi = lane & 15, quad = lane >> 4;     // mi = graph col
    int gblk = blockIdx.x;
    int g_abs = gblk * GPB + mi;
    int R0 = 16 * wv + 4 * quad;              // this lane's 4 h-rows [R0, R0+4)

    // fragment-order write slot for rows R0..R0+3 of graph mi:
    //   row R -> (ks=R>>5, lane'=mi+16*((R>>3)&3), j=R&7); reg r=0..3 -> j0+r.
    int eW = (((wv >> 1) * 64) + (mi + 16 * ((2 * wv + (quad >> 1)) & 3))) * 8
             + 4 * (quad & 1);

    // W_hh A-fragments, register-resident: 3 tiles (r,z,n), 4 ks each = 48 VGPR.
    // Pre-scaled: r,z by log2e; n by 2*log2e (exact, folded into bf16 quantize).
    bf16x8 wfr[3][4];
#pragma unroll
    for (int gate = 0; gate < 3; ++gate) {
        int T = wv + 8 * gate;
        float sc = (gate == 2) ? K_2LOG2E : K_LOG2E;
#pragma unroll
        for (int ks = 0; ks < 4; ++ks) {
            const float* wp = w_hh + (size_t)(16 * T + mi) * H + quad * 8 + ks * 32;
            float4 f0 = *(const float4*)wp;
            float4 f1 = *(const float4*)(wp + 4);
            bf16x8 v;
            v[0] = (short)f2b(f0.x * sc); v[1] = (short)f2b(f0.y * sc);
            v[2] = (short)f2b(f0.z * sc); v[3] = (short)f2b(f0.w * sc);
            v[4] = (short)f2b(f1.x * sc); v[5] = (short)f2b(f1.y * sc);
            v[6] = (short)f2b(f1.z * sc); v[7] = (short)f2b(f1.w * sc);
            wfr[gate][ks] = v;
        }
    }
    float4 bn = *(const float4*)(b_hh + 256 + R0);     // n-gate bias (acc seed)
    float4 h0 = *(const float4*)(hG + (size_t)g_abs * H + R0);
    int ls = len_seq[g_abs];

    float hp[4]  = {h0.x, h0.y, h0.z, h0.w};
    float bnn[4] = {bn.x * K_2LOG2E, bn.y * K_2LOG2E, bn.z * K_2LOG2E, bn.w * K_2LOG2E};

    auto storeh = [&](int buf, const float* hv) {
        u32 w0 = cvtpk(hv[0], hv[1]);
        u32 w1 = cvtpk(hv[2], hv[3]);
        *(uint2*)&hA[buf * 2048 + eW] = make_uint2(w0, w1);
    };
    auto loadxw = [&](int t, u16x4* d) {
        const u16* p = xw2 + ((((size_t)gblk * LL + t) * 8 + wv) * 3) * 256
                     + (quad << 6) + (mi << 2);
        d[0] = *(const u16x4*)(p);          // r   (512B coalesced per wave)
        d[1] = *(const u16x4*)(p + 256);    // z
        d[2] = *(const u16x4*)(p + 512);    // n
    };

    auto step = [&](int t, const u16x4* x, int buf) {
        f32x4 acc[3];
        acc[0] = (f32x4){0.f, 0.f, 0.f, 0.f};
        acc[1] = (f32x4){0.f, 0.f, 0.f, 0.f};
        acc[2] = (f32x4){bnn[0], bnn[1], bnn[2], bnn[3]};
#pragma unroll
        for (int ks = 0; ks < 4; ++ks) {
            const int e = (ks * 64 + lane) * 8;           // own 16B, conflict-free
            bf16x8 bh = *(const bf16x8*)&hA[buf * 2048 + e];
#pragma unroll
            for (int gate = 0; gate < 3; ++gate)
                acc[gate] = __builtin_amdgcn_mfma_f32_16x16x32_bf16(wfr[gate][ks], bh, acc[gate], 0, 0, 0);
        }
        float hv[4];
        float4 so;
#pragma unroll
        for (int r = 0; r < 4; ++r) {
            float xr = b2f(x[0][r]);                      // pre-scaled by log2e
            float xz = b2f(x[1][r]);
            float xn = b2f(x[2][r]);                      // pre-scaled by 2log2e
            float rg = rcpf(1.f + __builtin_amdgcn_exp2f(-(xr + acc[0][r])));
            float zg = rcpf(1.f + __builtin_amdgcn_exp2f(-(xz + acc[1][r])));
            float u  = xn + rg * acc[2][r];               // = 2*log2e*(true u)
            float ng = 1.f - 2.f * rcpf(__builtin_amdgcn_exp2f(u) + 1.f);
            float hn = ng + zg * (hp[r] - ng);
            hp[r] = hn;
            hv[r] = hn;
            ((float*)&so)[r] = (t < ls) ? hn : 0.f;       // pad_packed mask
        }
        *(float4*)(soutG + ((size_t)g_abs * LL + t) * H + R0) = so;
        storeh(buf ^ 1, hv);
    };

    u16x4 xa[3], xb[3];
    loadxw(0, xa);
    loadxw(1, xb);
    storeh(0, hp);
    asm volatile("s_waitcnt lgkmcnt(0)\n\ts_barrier" ::: "memory");

    for (int t = 0; t < LL; t += 2) {
        step(t, xa, 0);
        if (t + 2 < LL) loadxw(t + 2, xa);
        // LDS-only barrier: do NOT drain vmcnt (stores/prefetch stay in flight)
        asm volatile("s_waitcnt lgkmcnt(0)\n\ts_barrier" ::: "memory");
        step(t + 1, xb, 1);
        if (t + 3 < LL) loadxw(t + 3, xb);
        asm volatile("s_waitcnt lgkmcnt(0)\n\ts_barrier" ::: "memory");
    }
}

// ---------------- A2[row,:] = W1a @ sout[row]  (rows = b*48+t), f32 out ----------------
__global__ __launch_bounds__(256) void k_a2(const float* __restrict__ soutG,
                                            const float* __restrict__ linN_w,
                                            float* __restrict__ A2) {
    __shared__ float wb[32][130];
    __shared__ float xl[16][H];
    int tid = threadIdx.x;
    int n0 = blockIdx.x * 16;
    for (int idx = tid; idx < 16 * H; idx += 256)
        xl[idx >> 7][idx & 127] = soutG[(size_t)n0 * H + idx];
    int col = tid & 127, g = tid >> 7;
    float acc[8] = {0.f, 0.f, 0.f, 0.f, 0.f, 0.f, 0.f, 0.f};
    for (int c = 0; c < 4; ++c) {
        int k0 = c * 32;
        __syncthreads();
        for (int idx = tid; idx < 32 * H; idx += 256) {
            int r = idx >> 5, kk = idx & 31;
            wb[kk][r] = linN_w[(size_t)r * (2 * H) + k0 + kk];
        }
        __syncthreads();
#pragma unroll
        for (int kk = 0; kk < 32; ++kk) {
            float w = wb[kk][col];
#pragma unroll
            for (int j = 0; j < 8; ++j) acc[j] += xl[g * 8 + j][k0 + kk] * w;
        }
    }
#pragma unroll
    for (int j = 0; j < 8; ++j)
        A2[(size_t)(n0 + g * 8 + j) * H + col] = acc[j];
}

// ---------------- logits[n][t] = sum_k w2[k]*relu(A2[t][k]+Bx[n][k]) ----------------
__global__ __launch_bounds__(256) void k_logits(const float* __restrict__ A2,
                                                const u16* __restrict__ BxU,
                                                const float* __restrict__ linNf_w,
                                                float* __restrict__ logits) {
    __shared__ float a2s[LL][130];
    __shared__ float bxs[16][130];
    __shared__ float w2s[H];
    int tid = threadIdx.x;
    int g = blockIdx.x >> 3, tile = blockIdx.x & 7;
    int n0g = g * NPG + tile * 16;

    for (int i2 = tid; i2 < LL * 64; i2 += 256) {
        int r = i2 >> 6, c2 = i2 & 63;
        *(float2*)&a2s[r][2 * c2] = *(const float2*)(A2 + ((size_t)g * LL + r) * H + 2 * c2);
    }
    for (int iu = tid; iu < 16 * 64; iu += 256) {
        int r = iu >> 6, c = iu & 63;
        float2 v = up2(((const u32*)BxU)[(size_t)(n0g + r) * 64 + c]);
        *(float2*)&bxs[r][2 * c] = v;
    }
    if (tid < H) w2s[tid] = linNf_w[tid];
    __syncthreads();

    int n = tid & 15, tt = tid >> 4;
#pragma unroll
    for (int pass = 0; pass < 3; ++pass) {
        int t = tt + 16 * pass;
        float acc = 0.f;
#pragma unroll
        for (int kp = 0; kp < 64; ++kp) {
            float2 a2 = *(const float2*)&a2s[t][2 * kp];
            float2 bx = *(const float2*)&bxs[n][2 * kp];
            float2 w  = *(const float2*)&w2s[2 * kp];
            acc += w.x * fmaxf(a2.x + bx.x, 0.f) + w.y * fmaxf(a2.y + bx.y, 0.f);
        }
        logits[(size_t)(n0g + n) * LL + t] = acc;
    }
}

// ---------------- per-(graph,t) softmax over nodes; write output ----------------
__global__ __launch_bounds__(256) void k_softmax(const float* __restrict__ logits,
                                                 float* __restrict__ out) {
    __shared__ float lg[NPG][LL + 1];
    __shared__ float pm[4][LL], ps[4][LL];
    __shared__ float mv[LL], inv[LL];
    int b = blockIdx.x, tid = threadIdx.x;
    int n0 = b * NPG;
    for (int idx = tid; idx < NPG * LL; idx += 256) {
        int n = idx / LL, t = idx - n * LL;
        lg[n][t] = logits[(size_t)n0 * LL + idx];
    }
    __syncthreads();
    int t = tid & 63, seg = tid >> 6;
    if (t < LL) {
        float m = -1e30f;
        int nb = seg * 32;
        for (int n = nb; n < nb + 32; ++n) m = fmaxf(m, lg[n][t]);
        pm[seg][t] = m;
    }
    __syncthreads();
    if (tid < LL)
        mv[tid] = fmaxf(fmaxf(pm[0][tid], pm[1][tid]), fmaxf(pm[2][tid], pm[3][tid]));
    __syncthreads();
    if (t < LL) {
        float m = mv[t], s = 0.f;
        int nb = seg * 32;
        for (int n = nb; n < nb + 32; ++n) {
            float e = __expf(lg[n][t] - m);
            lg[n][t] = e;
            s += e;
        }
        ps[seg][t] = s;
    }
    __syncthreads();
    if (tid < LL)
        inv[tid] = 1.f / (ps[0][tid] + ps[1][tid] + ps[2][tid] + ps[3][tid]);
    __syncthreads();
    for (int idx = tid; idx < NPG * LL; idx += 256) {
        int n = idx / LL, tc = idx - n * LL;
        out[(size_t)BB * VA + (size_t)n0 * LL + idx] = lg[n][tc] * inv[tc];
    }
}

// ---------------- launch ----------------
extern "C" void kernel_launch(void* const* d_in, const int* in_sizes, int n_in,
                              void* d_out, int out_size, void* d_ws, size_t ws_size,
                              hipStream_t stream) {
    (void)in_sizes; (void)n_in; (void)out_size; (void)ws_size;
    const int*   nodeTypes    = (const int*)d_in[0];
    const int*   edge_index   = (const int*)d_in[1];
    const int*   edge_attr    = (const int*)d_in[2];
    const int*   nodes_bs     = (const int*)d_in[4];
    const int*   len_seq      = (const int*)d_in[5];
    const float* seq_in       = (const float*)d_in[6];
    const int*   action_input = (const int*)d_in[7];
    const float* emb_nodes    = (const float*)d_in[8];
    const float* emb_actions  = (const float*)d_in[9];
    const float* rgcn_rel     = (const float*)d_in[10];
    const float* rgcn_root    = (const float*)d_in[11];
    const float* rgcn_bias    = (const float*)d_in[12];
    const float* gru_w_ih     = (const float*)d_in[13];
    const float* gru_w_hh     = (const float*)d_in[14];
    const float* gru_b_ih     = (const float*)d_in[15];
    const float* gru_b_hh     = (const float*)d_in[16];
    const float* linA_w       = (const float*)d_in[17];
    const float* linA_b       = (const float*)d_in[18];
    const float* linAf_w      = (const float*)d_in[19];
    const float* linAf_b      = (const float*)d_in[20];
    const float* linN_w       = (const float*)d_in[21];
    const float* linN_b       = (const float*)d_in[22];
    const float* linNf_w      = (const float*)d_in[23];
    // linNf_b cancels in the softmax

    char* w = (char*)d_ws;
    float* x0      = (float*)(w + 0);          // [0,4MB) emb ping; dead after rgcn L3
    u16*   xwG     = (u16*)  (w + 0);          //   overlay (after L3): [0, 2,359,296)
    float* logitsW = (float*)(w + 0);          //   overlay (after k_gru_bx): [0, 1,572,864)
    float* soutG   = (float*)(w + 2359296);    //   overlay (after L3): [.., 3,932,160)
    float* x1      = (float*)(w + 4194304);    // [4MB,8MB) final x f32 (live to end)
    float* igG     = (float*)(w + 8388608);    // [8MB, 9,961,472) shifted GRU input
    float* A2      = (float*)(w + 8388608);    //   overlay (igG dead before k_a2)
    u16*   BxU     = (u16*)  (w + 9961472);    // [9,961,472, 12,058,624)
    int*   bsum    = (int*)  (w + 9961472);    //   overlay on BxU (dead until k_gru_bx)
    float* hGsum   = (float*)(w + 9969664);    //   overlay on BxU + 8 KB (dead by k_gru_bx)
    int*   rowptr  = (int*)  (w + 11567104);   // dead after rgcn L3
    int*   fill    = (int*)  (w + 11829760);   // dead after scatter
    float* hG      = (float*)(w + 12058624);   // 32 KB (overlays fill tail; fill dead by then)
    int*   colidx  = (int*)  (w + 12091904);   // dead after rgcn L3
    u16*   WTih    = (u16*)  (w + 12354048);   // 96 KB gap slot (no alias with fill/colidx)
    u16*   WT      = (u16*)  (w + 12616192);   // rgcn weights bf16 (tiled), 884,736 B

    float* out_f = (float*)d_out;

    k_prep<<<dim3(5824), dim3(256), 0, stream>>>(nodeTypes, emb_nodes, rgcn_rel,
        rgcn_root, gru_w_ih, x0, WT, WTih, hGsum, fill);
    k_hist<<<dim3(256), dim3(256), 0, stream>>>(edge_index, edge_attr, fill);
    k_scan1<<<dim3(256), dim3(256), 0, stream>>>(fill, bsum);
    k_scan3<<<dim3(256), dim3(256), 0, stream>>>(bsum, fill, rowptr);
    k_scatter<<<dim3(256), dim3(256), 0, stream>>>(edge_index, edge_attr, fill, colidx);

    const int rg_grid = NN / RGN;   // 512
    k_rgcn<<<dim3(rg_grid), dim3(512), 0, stream>>>(x0, x1,
        WT + 0 * 147456, rgcn_bias + 0 * H, rowptr, colidx, nullptr);
    k_rgcn<<<dim3(rg_grid), dim3(512), 0, stream>>>(x1, x0,
        WT + 1 * 147456, rgcn_bias + 1 * H, rowptr, colidx, nullptr);
    k_rgcn<<<dim3(rg_grid), dim3(512), 0, stream>>>(x0, x1,
        WT + 2 * 147456, rgcn_bias + 2 * H, rowptr, colidx, hGsum);
    // x_final = x1 (x0 region free from here)

    k_pool_seq<<<dim3(2 * BB), dim3(256), 0, stream>>>(hGsum, nodes_bs, linA_w, linA_b,
        linAf_w, linAf_b, hG, out_f, x1, seq_in, emb_actions, action_input, igG);
    k_xw<<<dim3(BB * LL / 16), dim3(256), 0, stream>>>(igG, WTih, gru_b_ih, gru_b_hh, xwG);
    k_gru_bx<<<dim3(GRU_BLKS + BX_BLKS), dim3(512), 0, stream>>>(xwG, hG, gru_w_hh,
        gru_b_hh, len_seq, soutG, x1, linN_w, linN_b, BxU);
    k_a2<<<dim3(BB * LL / 16), dim3(256), 0, stream>>>(soutG, linN_w, A2);
    k_logits<<<dim3(BB * 8), dim3(256), 0, stream>>>(A2, BxU, linNf_w, logitsW);
    k_softmax<<<dim3(BB), dim3(256), 0, stream>>>(logitsW, out_f);
}